// Round 1
// baseline (630.808 us; speedup 1.0000x reference)
//
#include <hip/hip_runtime.h>
#include <math.h>

// ---- workspace layout (float offsets) ----
#define OFF_NWT   0
#define OFF_NKO   10
#define OFF_L1    20
#define OFF_L2    30
#define OFF_CNT   40
#define OFF_ZSUM  50
#define OFF_ZSQ   150
#define OFF_KSUM  160
#define OFF_REC   162
#define ACC_FLOATS 192

#define WP_OFF    256                       // packed W1 [2000][256]
#define H_OFF     (WP_OFF + 2000*256)       // H [8192][256] (enc 0-127 | kap 128-255)
#define Z_OFF     (H_OFF + 8192*256)        // Z [8192][10]
#define KAP_OFF   (Z_OFF + 8192*10)         // kappa per row [8192]

// ---------------- pack enc_w1|kap_w1 into [2000][256] ----------------
__global__ void pack_w_kernel(const float* __restrict__ enc_w1,
                              const float* __restrict__ kap_w1,
                              float* __restrict__ Wp)
{
    int idx = blockIdx.x * 256 + threadIdx.x;     // 512000 total
    int k = idx >> 8;
    int c = idx & 255;
    Wp[idx] = (c < 128) ? enc_w1[k*128 + c] : kap_w1[k*128 + (c - 128)];
}

// ---------------- class counts ----------------
__global__ void counts_kernel(const int* __restrict__ wtl, const int* __restrict__ kol,
                              float* __restrict__ acc)
{
    __shared__ int cw[10], ck[10];
    int t = threadIdx.x;
    if (t < 10) { cw[t] = 0; ck[t] = 0; }
    __syncthreads();
    for (int i = t; i < 4096; i += 1024) {
        atomicAdd(&cw[wtl[i]], 1);
        atomicAdd(&ck[kol[i]], 1);
    }
    __syncthreads();
    if (t < 10) { acc[OFF_NWT + t] = (float)cw[t]; acc[OFF_NKO + t] = (float)ck[t]; }
}

// ---------------- GEMM1: H[8192][256] = X[8192][2000] @ Wp[2000][256] ----------------
// BM=32, BN=256, BK=16; 256 threads; grid 256 blocks.
__global__ __launch_bounds__(256) void gemm1_kernel(const float* __restrict__ wt_x,
                                                    const float* __restrict__ ko_x,
                                                    const float* __restrict__ Wp,
                                                    float* __restrict__ Hb)
{
    __shared__ float Xs[16][32];
    __shared__ float Ws[16][256];
    int R0 = blockIdx.x * 32;
    const float* xb = (R0 < 4096) ? (wt_x + (size_t)R0 * 2000)
                                  : (ko_x + (size_t)(R0 - 4096) * 2000);
    int t = threadIdx.x;
    int ty = t >> 5;      // 0..7  -> rows ty*4 .. ty*4+3
    int tx = t & 31;      // cols tx + 32*j
    float acc[4][8];
#pragma unroll
    for (int i = 0; i < 4; ++i)
#pragma unroll
        for (int j = 0; j < 8; ++j) acc[i][j] = 0.f;

    for (int k0 = 0; k0 < 2000; k0 += 16) {
        if (t < 128) {
            int m = t >> 2, kk = (t & 3) << 2;
            float4 xv = *(const float4*)(xb + (size_t)m * 2000 + k0 + kk);
            Xs[kk + 0][m] = xv.x; Xs[kk + 1][m] = xv.y;
            Xs[kk + 2][m] = xv.z; Xs[kk + 3][m] = xv.w;
        }
        const float4* wsrc = (const float4*)(Wp + (size_t)k0 * 256);
        float4* wdst = (float4*)(&Ws[0][0]);
        wdst[t]       = wsrc[t];
        wdst[t + 256] = wsrc[t + 256];
        wdst[t + 512] = wsrc[t + 512];
        wdst[t + 768] = wsrc[t + 768];
        __syncthreads();
#pragma unroll
        for (int kk = 0; kk < 16; ++kk) {
            float4 xv = *(const float4*)(&Xs[kk][ty * 4]);
            float xr[4] = {xv.x, xv.y, xv.z, xv.w};
#pragma unroll
            for (int j = 0; j < 8; ++j) {
                float wv = Ws[kk][tx + 32 * j];
#pragma unroll
                for (int i = 0; i < 4; ++i) acc[i][j] = fmaf(xr[i], wv, acc[i][j]);
            }
        }
        __syncthreads();
    }
#pragma unroll
    for (int i = 0; i < 4; ++i)
#pragma unroll
        for (int j = 0; j < 8; ++j)
            Hb[(size_t)(R0 + ty * 4 + i) * 256 + tx + 32 * j] = acc[i][j];
}

// ---------------- stage2: LN->ReLU->head matmuls per row ----------------
// block 128 = 2 waves: wave0 enc head -> z ; wave1 kap head -> kappa
__global__ __launch_bounds__(128) void stage2_kernel(const float* __restrict__ Hb,
    const float* __restrict__ enc_b1, const float* __restrict__ enc_g, const float* __restrict__ enc_be,
    const float* __restrict__ enc_w2, const float* __restrict__ enc_b2,
    const float* __restrict__ kap_b1, const float* __restrict__ kap_g, const float* __restrict__ kap_be,
    const float* __restrict__ kap_w2, const float* __restrict__ kap_b2,
    float* __restrict__ Z, float* __restrict__ Kap)
{
    __shared__ float sh[128];
    int row  = blockIdx.x;           // 0..8191
    int wave = threadIdx.x >> 6;     // 0 enc, 1 kap
    int lane = threadIdx.x & 63;
    const float* hb = Hb + (size_t)row * 256 + wave * 128;
    const float* b1 = wave ? kap_b1 : enc_b1;
    const float* gg = wave ? kap_g  : enc_g;
    const float* bb = wave ? kap_be : enc_be;

    float h0 = hb[lane]      + b1[lane];
    float h1 = hb[lane + 64] + b1[lane + 64];
    float s = h0 + h1;
#pragma unroll
    for (int o = 32; o > 0; o >>= 1) s += __shfl_xor(s, o, 64);
    float m = s * (1.f / 128.f);
    float d0 = h0 - m, d1 = h1 - m;
    float v = d0 * d0 + d1 * d1;
#pragma unroll
    for (int o = 32; o > 0; o >>= 1) v += __shfl_xor(v, o, 64);
    v *= (1.f / 128.f);
    float sc = 1.f / sqrtf(v + 1e-5f);
    float r0 = fmaxf(fmaf(d0 * sc, gg[lane],      bb[lane]),      0.f);
    float r1 = fmaxf(fmaf(d1 * sc, gg[lane + 64], bb[lane + 64]), 0.f);

    if (wave == 0) { sh[lane] = r0; sh[lane + 64] = r1; }
    __syncthreads();

    if (wave == 0) {
        float mu = 0.f;
        if (lane < 10) {
            mu = enc_b2[lane];
            for (int c = 0; c < 128; ++c) mu = fmaf(sh[c], enc_w2[c * 10 + lane], mu);
        }
        float n2 = mu * mu;
#pragma unroll
        for (int o = 8; o > 0; o >>= 1) n2 += __shfl_xor(n2, o, 16);
        float inv = 1.f / fmaxf(sqrtf(n2), 1e-12f);
        if (lane < 10) Z[(size_t)row * 10 + lane] = mu * inv;
    } else {
        float p = r0 * kap_w2[lane] + r1 * kap_w2[lane + 64];
#pragma unroll
        for (int o = 32; o > 0; o >>= 1) p += __shfl_xor(p, o, 64);
        if (lane == 0) {
            float x = p + kap_b2[0];
            float sp = (x > 20.f) ? x : log1pf(expf(x));
            Kap[row] = sp + 1e-6f;
        }
    }
}

// ---------------- contrastive pass (one wave per A-row) ----------------
// Row i contributes only to its own class ci: sumexp & sum of S over B-cols of class ci.
__global__ __launch_bounds__(256) void contrast_kernel(const float* __restrict__ ZA,
                                                       const int* __restrict__ yA,
                                                       const float* __restrict__ ZB,
                                                       const int* __restrict__ yB,
                                                       const float* __restrict__ nB,
                                                       float* __restrict__ outc)
{
    int i    = blockIdx.x * 4 + (threadIdx.x >> 6);
    int lane = threadIdx.x & 63;
    int ci = yA[i];
    float nb = nB[ci];
    float za[10];
#pragma unroll
    for (int d = 0; d < 10; ++d) za[d] = ZA[(size_t)i * 10 + d];
    float se = 0.f, ss = 0.f;
    for (int j = lane; j < 4096; j += 64) {
        if (yB[j] == ci) {
            const float* zb = ZB + (size_t)j * 10;
            float s = 0.f;
#pragma unroll
            for (int d = 0; d < 10; ++d) s = fmaf(za[d], zb[d], s);
            s *= 10.f;                       // 1/TAU
            se += expf(s - 10.f);            // |S| <= 10 -> no online max needed
            ss += s;
        }
    }
#pragma unroll
    for (int o = 32; o > 0; o >>= 1) { se += __shfl_xor(se, o, 64); ss += __shfl_xor(ss, o, 64); }
    if (lane == 0 && nb > 0.5f) {
        float lse = 10.f + logf(se);
        atomicAdd(&outc[ci], lse - ss / nb);
    }
}

// ---------------- alignment stats + kappa reduction ----------------
__global__ __launch_bounds__(256) void align_kernel(const float* __restrict__ Z,
                                                    const int* __restrict__ wtl,
                                                    const int* __restrict__ kol,
                                                    const float* __restrict__ Kap,
                                                    float* __restrict__ acc)
{
    __shared__ float cL[10], qL[10], sL[100], ks;
    int t = threadIdx.x;
    if (t < 10) { cL[t] = 0.f; qL[t] = 0.f; }
    if (t < 100) sL[t] = 0.f;
    if (t == 0) ks = 0.f;
    __syncthreads();
    int row = blockIdx.x * 256 + t;                 // 0..8191
    int c = (row < 4096) ? wtl[row] : kol[row - 4096];
    float zz[10]; float q = 0.f;
#pragma unroll
    for (int d = 0; d < 10; ++d) { zz[d] = Z[(size_t)row * 10 + d]; q = fmaf(zz[d], zz[d], q); }
    atomicAdd(&cL[c], 1.f);
    atomicAdd(&qL[c], q);
#pragma unroll
    for (int d = 0; d < 10; ++d) atomicAdd(&sL[c * 10 + d], zz[d]);
    atomicAdd(&ks, Kap[row]);
    __syncthreads();
    if (t < 10)  { atomicAdd(&acc[OFF_CNT + t], cL[t]); atomicAdd(&acc[OFF_ZSQ + t], qL[t]); }
    if (t < 100) atomicAdd(&acc[OFF_ZSUM + t], sL[t]);
    if (t == 0)  atomicAdd(&acc[OFF_KSUM + (blockIdx.x >= 16)], ks);
}

// ---------------- decoder + fused recon loss ----------------
// 32 rows/block; phase A: a=ReLU(LN(z@dec_w1+b1)) transposed in LDS;
// phase B: per 128-col chunk, 4x4 register outer-product, squared error vs x.
__global__ __launch_bounds__(256) void decoder_kernel(
    const float* __restrict__ wt_x, const float* __restrict__ ko_x,
    const float* __restrict__ Zb,
    const float* __restrict__ dw1, const float* __restrict__ db1,
    const float* __restrict__ dg,  const float* __restrict__ dbe,
    const float* __restrict__ dw2, const float* __restrict__ db2,
    float* __restrict__ acc)
{
    __shared__ float aT[128][32];    // [c][row]
    __shared__ float wL[128][128];   // [c][jj]
    __shared__ float rs[4];
    int t = threadIdx.x;
    int r0 = blockIdx.x * 32;
    {
        int lrow = t >> 3;           // 0..31
        int tc   = t & 7;            // 0..7 ; cols tc + 8*i
        int row = r0 + lrow;
        const float* zr = Zb + (size_t)row * 10;
        float z[10];
#pragma unroll
        for (int d = 0; d < 10; ++d) z[d] = zr[d];
        float h[16];
#pragma unroll
        for (int i = 0; i < 16; ++i) {
            int c = tc + 8 * i;
            float a = db1[c];
#pragma unroll
            for (int d = 0; d < 10; ++d) a = fmaf(z[d], dw1[d * 128 + c], a);
            h[i] = a;
        }
        float s = 0.f;
#pragma unroll
        for (int i = 0; i < 16; ++i) s += h[i];
#pragma unroll
        for (int o = 4; o > 0; o >>= 1) s += __shfl_xor(s, o, 8);
        float m = s * (1.f / 128.f);
        float v = 0.f;
#pragma unroll
        for (int i = 0; i < 16; ++i) { float d_ = h[i] - m; v = fmaf(d_, d_, v); }
#pragma unroll
        for (int o = 4; o > 0; o >>= 1) v += __shfl_xor(v, o, 8);
        v *= (1.f / 128.f);
        float sc = 1.f / sqrtf(v + 1e-5f);
#pragma unroll
        for (int i = 0; i < 16; ++i) {
            int c = tc + 8 * i;
            aT[c][lrow] = fmaxf(fmaf((h[i] - m) * sc, dg[c], dbe[c]), 0.f);
        }
    }
    __syncthreads();

    int rg = t >> 5;    // 0..7 -> rows rg*4..+3
    int cg = t & 31;    // cols cg*4..+3 within chunk
    float rsum = 0.f;
    for (int j0 = 0; j0 < 2000; j0 += 128) {
        for (int f = t; f < 4096; f += 256) {
            int c  = f >> 5;
            int jj = (f & 31) << 2;
            float4 wv;
            if (j0 + jj < 2000) wv = *(const float4*)(dw2 + (size_t)c * 2000 + j0 + jj);
            else                wv = make_float4(0.f, 0.f, 0.f, 0.f);
            *(float4*)(&wL[c][jj]) = wv;
        }
        __syncthreads();
        float a4[4][4];
#pragma unroll
        for (int i = 0; i < 4; ++i)
#pragma unroll
            for (int j = 0; j < 4; ++j) a4[i][j] = 0.f;
#pragma unroll 8
        for (int c = 0; c < 128; ++c) {
            float4 av = *(const float4*)(&aT[c][rg * 4]);
            float4 wv = *(const float4*)(&wL[c][cg * 4]);
            float ar[4] = {av.x, av.y, av.z, av.w};
            float wr[4] = {wv.x, wv.y, wv.z, wv.w};
#pragma unroll
            for (int i = 0; i < 4; ++i)
#pragma unroll
                for (int j = 0; j < 4; ++j) a4[i][j] = fmaf(ar[i], wr[j], a4[i][j]);
        }
        int jb = j0 + cg * 4;
        if (jb < 2000) {
            float4 b4 = *(const float4*)(db2 + jb);
            float br[4] = {b4.x, b4.y, b4.z, b4.w};
#pragma unroll
            for (int i = 0; i < 4; ++i) {
                int row = r0 + rg * 4 + i;
                const float* xrow = (row < 4096) ? (wt_x + (size_t)row * 2000)
                                                 : (ko_x + (size_t)(row - 4096) * 2000);
                float4 x4 = *(const float4*)(xrow + jb);
                float xr[4] = {x4.x, x4.y, x4.z, x4.w};
#pragma unroll
                for (int j = 0; j < 4; ++j) {
                    float d_ = a4[i][j] + br[j] - xr[j];
                    rsum = fmaf(d_, d_, rsum);
                }
            }
        }
        __syncthreads();
    }
#pragma unroll
    for (int o = 32; o > 0; o >>= 1) rsum += __shfl_xor(rsum, o, 64);
    if ((t & 63) == 0) rs[t >> 6] = rsum;
    __syncthreads();
    if (t == 0) atomicAdd(&acc[OFF_REC], rs[0] + rs[1] + rs[2] + rs[3]);
}

// ---------------- finalize ----------------
__global__ void finalize_kernel(const float* __restrict__ acc, float* __restrict__ out)
{
    float total = 0.f, nsh = 0.f;
    for (int c = 0; c < 10; ++c) {
        float nw = acc[OFF_NWT + c], nk = acc[OFF_NKO + c];
        if (nw > 0.5f && nk > 0.5f) {
            float l1 = acc[OFF_L1 + c] / nw;
            float l2 = acc[OFF_L2 + c] / nk;
            total += 0.5f * (l1 + l2);
            nsh += 1.f;
        }
    }
    float contrast = (nsh > 0.f) ? total / nsh : 0.f;
    float ap = 0.f, np_ = 0.f;
    for (int c = 0; c < 10; ++c) {
        float cn = acc[OFF_CNT + c];
        if (cn > 0.5f) {
            float mu2 = 0.f;
            for (int d = 0; d < 10; ++d) {
                float mm = acc[OFF_ZSUM + c * 10 + d] / cn;
                mu2 = fmaf(mm, mm, mu2);
            }
            ap += acc[OFF_ZSQ + c] / cn - mu2;
            np_ += 1.f;
        }
    }
    float align = (np_ > 0.f) ? ap / np_ : 0.f;
    float kl = 0.01f * (acc[OFF_KSUM + 0] + acc[OFF_KSUM + 1]) * (1.f / 4096.f);
    float recon = acc[OFF_REC] * (1.f / 8192000.f);
    out[0] = recon + kl + 1.0f * contrast + 0.5f * align;
}

extern "C" void kernel_launch(void* const* d_in, const int* in_sizes, int n_in,
                              void* d_out, int out_size, void* d_ws, size_t ws_size,
                              hipStream_t stream)
{
    const float* wt_x   = (const float*)d_in[0];
    const float* ko_x   = (const float*)d_in[1];
    const int*   wtl    = (const int*)d_in[2];
    const int*   kol    = (const int*)d_in[3];
    const float* enc_w1 = (const float*)d_in[4];
    const float* enc_b1 = (const float*)d_in[5];
    const float* enc_g  = (const float*)d_in[6];
    const float* enc_be = (const float*)d_in[7];
    const float* enc_w2 = (const float*)d_in[8];
    const float* enc_b2 = (const float*)d_in[9];
    const float* kap_w1 = (const float*)d_in[10];
    const float* kap_b1 = (const float*)d_in[11];
    const float* kap_g  = (const float*)d_in[12];
    const float* kap_be = (const float*)d_in[13];
    const float* kap_w2 = (const float*)d_in[14];
    const float* kap_b2 = (const float*)d_in[15];
    const float* dw1    = (const float*)d_in[16];
    const float* db1    = (const float*)d_in[17];
    const float* dg     = (const float*)d_in[18];
    const float* dbe    = (const float*)d_in[19];
    const float* dw2    = (const float*)d_in[20];
    const float* db2    = (const float*)d_in[21];

    float* ws  = (float*)d_ws;
    float* acc = ws;
    float* Wp  = ws + WP_OFF;
    float* Hb  = ws + H_OFF;
    float* Zb  = ws + Z_OFF;
    float* Kap = ws + KAP_OFF;

    hipMemsetAsync(acc, 0, ACC_FLOATS * sizeof(float), stream);
    pack_w_kernel<<<2000, 256, 0, stream>>>(enc_w1, kap_w1, Wp);
    counts_kernel<<<1, 1024, 0, stream>>>(wtl, kol, acc);
    gemm1_kernel<<<256, 256, 0, stream>>>(wt_x, ko_x, Wp, Hb);
    stage2_kernel<<<8192, 128, 0, stream>>>(Hb, enc_b1, enc_g, enc_be, enc_w2, enc_b2,
                                            kap_b1, kap_g, kap_be, kap_w2, kap_b2, Zb, Kap);
    contrast_kernel<<<1024, 256, 0, stream>>>(Zb, wtl, Zb + 4096 * 10, kol, acc + OFF_NKO, acc + OFF_L1);
    contrast_kernel<<<1024, 256, 0, stream>>>(Zb + 4096 * 10, kol, Zb, wtl, acc + OFF_NWT, acc + OFF_L2);
    align_kernel<<<32, 256, 0, stream>>>(Zb, wtl, kol, Kap, acc);
    decoder_kernel<<<256, 256, 0, stream>>>(wt_x, ko_x, Zb, dw1, db1, dg, dbe, dw2, db2, acc);
    finalize_kernel<<<1, 1, 0, stream>>>(acc, (float*)d_out);
}

// Round 2
// 601.116 us; speedup vs baseline: 1.0494x; 1.0494x over previous
//
#include <hip/hip_runtime.h>
#include <math.h>

typedef __attribute__((ext_vector_type(8))) __bf16 bf16x8;
typedef __attribute__((ext_vector_type(4))) float f32x4;

// ---- workspace layout (float offsets) ----
#define OFF_NWT   0
#define OFF_NKO   10
#define OFF_L1    20
#define OFF_L2    30
#define OFF_CNT   40
#define OFF_ZSUM  50
#define OFF_ZSQ   150
#define OFF_KSUM  160
#define OFF_REC   162
#define ACC_FLOATS 192

#define WT_OFF    256                        // WThi [256][2048] bf16 = 262144 floats
#define WTLO_OFF  (WT_OFF + 262144)          // WTlo
#define H_OFF     (WTLO_OFF + 262144)        // H [8192][256] fp32 (enc 0-127 | kap 128-255)
#define Z_OFF     (H_OFF + 8192*256)         // Z [8192][10]
#define KAP_OFF   (Z_OFF + 8192*10)          // kappa [8192]

// ---------------- pack: transpose + bf16 hi/lo split of [enc_w1|kap_w1] ----------------
// WThi/WTlo layout: [col 0..255][k 0..2047] bf16, zero-padded for k>=2000.
__global__ __launch_bounds__(256) void pack_w_kernel(const float* __restrict__ enc_w1,
                                                     const float* __restrict__ kap_w1,
                                                     __bf16* __restrict__ WThi,
                                                     __bf16* __restrict__ WTlo)
{
    __shared__ float tile[64][65];
    int kt = blockIdx.x & 31;          // 32 k-tiles of 64
    int ct = blockIdx.x >> 5;          // 4 c-tiles of 64
    int k0 = kt * 64, c0 = ct * 64;
    int t = threadIdx.x;
    int lr = t >> 6, lc = t & 63;
    // load phase: coalesced along c; store transposed into LDS
#pragma unroll
    for (int i = 0; i < 16; ++i) {
        int k = k0 + lr + 4 * i;
        int c = c0 + lc;
        float v = 0.f;
        if (k < 2000) v = (c < 128) ? enc_w1[(size_t)k * 128 + c]
                                    : kap_w1[(size_t)k * 128 + (c - 128)];
        tile[lc][lr + 4 * i] = v;
    }
    __syncthreads();
    // write phase: coalesced along k
#pragma unroll
    for (int i = 0; i < 16; ++i) {
        int c = c0 + lr + 4 * i;
        int k = k0 + lc;
        float v = tile[lr + 4 * i][lc];
        __bf16 h = (__bf16)v;
        __bf16 l = (__bf16)(v - (float)h);
        size_t idx = (size_t)c * 2048 + k;
        WThi[idx] = h;
        WTlo[idx] = l;
    }
}

// ---------------- class counts ----------------
__global__ void counts_kernel(const int* __restrict__ wtl, const int* __restrict__ kol,
                              float* __restrict__ acc)
{
    __shared__ int cw[10], ck[10];
    int t = threadIdx.x;
    if (t < 10) { cw[t] = 0; ck[t] = 0; }
    __syncthreads();
    for (int i = t; i < 4096; i += 1024) {
        atomicAdd(&cw[wtl[i]], 1);
        atomicAdd(&ck[kol[i]], 1);
    }
    __syncthreads();
    if (t < 10) { acc[OFF_NWT + t] = (float)cw[t]; acc[OFF_NKO + t] = (float)ck[t]; }
}

// ---------------- GEMM1 (MFMA bf16x3): H[8192][256] = X[8192][2000] @ W[2000][256] ----------------
// BM=32, BN=256, BK=32, grid 256 blocks x 512 thr (8 waves = 2m x 4n, wave tile 16x64).
// A: per-lane global fp32 -> in-reg hi/lo bf16. B: LDS double-buffered from pre-split WT.
__global__ __launch_bounds__(512) void gemm1_kernel(const float* __restrict__ wt_x,
                                                    const float* __restrict__ ko_x,
                                                    const __bf16* __restrict__ WThi,
                                                    const __bf16* __restrict__ WTlo,
                                                    float* __restrict__ Hb)
{
    __shared__ short Bs[2][2][8192];   // [buf][hi/lo][unit*8 shorts] = 64 KB
    int t = threadIdx.x;
    int widx = t >> 6, lane = t & 63;
    int wm = widx >> 2, wn = widx & 3;
    int R0 = blockIdx.x * 32;
    const float* xb = (R0 < 4096) ? (wt_x + (size_t)R0 * 2000)
                                  : (ko_x + (size_t)(R0 - 4096) * 2000);
    int arow = wm * 16 + (lane & 15);
    const float* xrow = xb + (size_t)arow * 2000;
    int kboff = (lane >> 4) * 8;

    // B-staging per-thread constants (swizzled source offsets, linear LDS dest)
    int cc0 = (t >> 2) & 15;
    int s0  = (t & 3) ^ ((cc0 >> 1) & 3);
    int col0 = (t >> 6) * 16 + cc0;
    size_t boff0 = (size_t)col0 * 2048 + s0 * 8;
    size_t boff1 = boff0 + (size_t)128 * 2048;

    f32x4 acc[4];
#pragma unroll
    for (int nf = 0; nf < 4; ++nf)
#pragma unroll
        for (int r = 0; r < 4; ++r) acc[nf][r] = 0.f;

    uint4 bh[2][2], bl[2][2];
    float4 aV0[2], aV1[2];

#define GLOADB(step, slot) do { \
    bh[slot][0] = *(const uint4*)(WThi + boff0 + (step) * 32); \
    bh[slot][1] = *(const uint4*)(WThi + boff1 + (step) * 32); \
    bl[slot][0] = *(const uint4*)(WTlo + boff0 + (step) * 32); \
    bl[slot][1] = *(const uint4*)(WTlo + boff1 + (step) * 32); } while (0)

#define DSWRITEB(buf, slot) do { \
    *(uint4*)&Bs[buf][0][t * 8]        = bh[slot][0]; \
    *(uint4*)&Bs[buf][0][4096 + t * 8] = bh[slot][1]; \
    *(uint4*)&Bs[buf][1][t * 8]        = bl[slot][0]; \
    *(uint4*)&Bs[buf][1][4096 + t * 8] = bl[slot][1]; } while (0)

#define GLOADA(step, slot) do { \
    int k0_ = (step) * 32; \
    int k_ = k0_ + kboff; \
    if (k0_ <= 1952) { \
        aV0[slot] = *(const float4*)(xrow + k_); \
        aV1[slot] = *(const float4*)(xrow + k_ + 4); \
    } else { \
        float a_[8]; \
        _Pragma("unroll") \
        for (int j = 0; j < 8; ++j) { int kk = k_ + j; a_[j] = (kk < 2000) ? xrow[kk] : 0.f; } \
        aV0[slot] = make_float4(a_[0], a_[1], a_[2], a_[3]); \
        aV1[slot] = make_float4(a_[4], a_[5], a_[6], a_[7]); } } while (0)

    // prologue: B(0),B(1),A(0),A(1) in flight; buf0 <- B(0)
    GLOADB(0, 0); GLOADA(0, 0);
    GLOADB(1, 1); GLOADA(1, 1);
    DSWRITEB(0, 0);
    __syncthreads();

    int cpr = lane & 15;
    int pph = (lane >> 4) ^ ((cpr >> 1) & 3);
    int ubase = (wn * 4) * 64 + cpr * 4 + pph;

    for (int st = 0; st < 64; ++st) {
        int cur = st & 1;
        // convert A(st) (frees its slot)
        bf16x8 ahi, alo;
        {
            float av[8] = {aV0[cur].x, aV0[cur].y, aV0[cur].z, aV0[cur].w,
                           aV1[cur].x, aV1[cur].y, aV1[cur].z, aV1[cur].w};
#pragma unroll
            for (int j = 0; j < 8; ++j) {
                __bf16 h = (__bf16)av[j];
                ahi[j] = h;
                alo[j] = (__bf16)(av[j] - (float)h);
            }
        }
        if (st + 2 < 64) { GLOADB(st + 2, cur); GLOADA(st + 2, cur); }
        if (st + 1 < 64) DSWRITEB(cur ^ 1, cur ^ 1);
#pragma unroll
        for (int nf = 0; nf < 4; ++nf) {
            bf16x8 bhf = *(const bf16x8*)&Bs[cur][0][(ubase + nf * 64) * 8];
            bf16x8 blf = *(const bf16x8*)&Bs[cur][1][(ubase + nf * 64) * 8];
            acc[nf] = __builtin_amdgcn_mfma_f32_16x16x32_bf16(ahi, bhf, acc[nf], 0, 0, 0);
            acc[nf] = __builtin_amdgcn_mfma_f32_16x16x32_bf16(alo, bhf, acc[nf], 0, 0, 0);
            acc[nf] = __builtin_amdgcn_mfma_f32_16x16x32_bf16(ahi, blf, acc[nf], 0, 0, 0);
        }
        __syncthreads();
    }

    // epilogue: C/D layout col=lane&15, row=(lane>>4)*4+r  [m89-verified]
#pragma unroll
    for (int nf = 0; nf < 4; ++nf)
#pragma unroll
        for (int r = 0; r < 4; ++r) {
            int row = R0 + wm * 16 + (lane >> 4) * 4 + r;
            int col = wn * 64 + nf * 16 + (lane & 15);
            Hb[(size_t)row * 256 + col] = acc[nf][r];
        }
#undef GLOADB
#undef DSWRITEB
#undef GLOADA
}

// ---------------- stage2: LN->ReLU->head matmuls per row ----------------
__global__ __launch_bounds__(128) void stage2_kernel(const float* __restrict__ Hb,
    const float* __restrict__ enc_b1, const float* __restrict__ enc_g, const float* __restrict__ enc_be,
    const float* __restrict__ enc_w2, const float* __restrict__ enc_b2,
    const float* __restrict__ kap_b1, const float* __restrict__ kap_g, const float* __restrict__ kap_be,
    const float* __restrict__ kap_w2, const float* __restrict__ kap_b2,
    float* __restrict__ Z, float* __restrict__ Kap)
{
    __shared__ float sh[128];
    int row  = blockIdx.x;
    int wave = threadIdx.x >> 6;
    int lane = threadIdx.x & 63;
    const float* hb = Hb + (size_t)row * 256 + wave * 128;
    const float* b1 = wave ? kap_b1 : enc_b1;
    const float* gg = wave ? kap_g  : enc_g;
    const float* bb = wave ? kap_be : enc_be;

    float h0 = hb[lane]      + b1[lane];
    float h1 = hb[lane + 64] + b1[lane + 64];
    float s = h0 + h1;
#pragma unroll
    for (int o = 32; o > 0; o >>= 1) s += __shfl_xor(s, o, 64);
    float m = s * (1.f / 128.f);
    float d0 = h0 - m, d1 = h1 - m;
    float v = d0 * d0 + d1 * d1;
#pragma unroll
    for (int o = 32; o > 0; o >>= 1) v += __shfl_xor(v, o, 64);
    v *= (1.f / 128.f);
    float sc = 1.f / sqrtf(v + 1e-5f);
    float r0 = fmaxf(fmaf(d0 * sc, gg[lane],      bb[lane]),      0.f);
    float r1 = fmaxf(fmaf(d1 * sc, gg[lane + 64], bb[lane + 64]), 0.f);

    if (wave == 0) { sh[lane] = r0; sh[lane + 64] = r1; }
    __syncthreads();

    if (wave == 0) {
        float mu = 0.f;
        if (lane < 10) {
            mu = enc_b2[lane];
            for (int c = 0; c < 128; ++c) mu = fmaf(sh[c], enc_w2[c * 10 + lane], mu);
        }
        float n2 = mu * mu;
#pragma unroll
        for (int o = 8; o > 0; o >>= 1) n2 += __shfl_xor(n2, o, 16);
        float inv = 1.f / fmaxf(sqrtf(n2), 1e-12f);
        if (lane < 10) Z[(size_t)row * 10 + lane] = mu * inv;
    } else {
        float p = r0 * kap_w2[lane] + r1 * kap_w2[lane + 64];
#pragma unroll
        for (int o = 32; o > 0; o >>= 1) p += __shfl_xor(p, o, 64);
        if (lane == 0) {
            float x = p + kap_b2[0];
            float sp = (x > 20.f) ? x : log1pf(expf(x));
            Kap[row] = sp + 1e-6f;
        }
    }
}

// ---------------- contrastive pass (one wave per A-row) ----------------
__global__ __launch_bounds__(256) void contrast_kernel(const float* __restrict__ ZA,
                                                       const int* __restrict__ yA,
                                                       const float* __restrict__ ZB,
                                                       const int* __restrict__ yB,
                                                       const float* __restrict__ nB,
                                                       float* __restrict__ outc)
{
    int i    = blockIdx.x * 4 + (threadIdx.x >> 6);
    int lane = threadIdx.x & 63;
    int ci = yA[i];
    float nb = nB[ci];
    float za[10];
#pragma unroll
    for (int d = 0; d < 10; ++d) za[d] = ZA[(size_t)i * 10 + d];
    float se = 0.f, ss = 0.f;
    for (int j = lane; j < 4096; j += 64) {
        if (yB[j] == ci) {
            const float* zb = ZB + (size_t)j * 10;
            float s = 0.f;
#pragma unroll
            for (int d = 0; d < 10; ++d) s = fmaf(za[d], zb[d], s);
            s *= 10.f;                       // 1/TAU
            se += expf(s - 10.f);            // |S| <= 10
            ss += s;
        }
    }
#pragma unroll
    for (int o = 32; o > 0; o >>= 1) { se += __shfl_xor(se, o, 64); ss += __shfl_xor(ss, o, 64); }
    if (lane == 0 && nb > 0.5f) {
        float lse = 10.f + logf(se);
        atomicAdd(&outc[ci], lse - ss / nb);
    }
}

// ---------------- alignment stats + kappa reduction ----------------
__global__ __launch_bounds__(256) void align_kernel(const float* __restrict__ Z,
                                                    const int* __restrict__ wtl,
                                                    const int* __restrict__ kol,
                                                    const float* __restrict__ Kap,
                                                    float* __restrict__ acc)
{
    __shared__ float cL[10], qL[10], sL[100], ks;
    int t = threadIdx.x;
    if (t < 10) { cL[t] = 0.f; qL[t] = 0.f; }
    if (t < 100) sL[t] = 0.f;
    if (t == 0) ks = 0.f;
    __syncthreads();
    int row = blockIdx.x * 256 + t;
    int c = (row < 4096) ? wtl[row] : kol[row - 4096];
    float zz[10]; float q = 0.f;
#pragma unroll
    for (int d = 0; d < 10; ++d) { zz[d] = Z[(size_t)row * 10 + d]; q = fmaf(zz[d], zz[d], q); }
    atomicAdd(&cL[c], 1.f);
    atomicAdd(&qL[c], q);
#pragma unroll
    for (int d = 0; d < 10; ++d) atomicAdd(&sL[c * 10 + d], zz[d]);
    atomicAdd(&ks, Kap[row]);
    __syncthreads();
    if (t < 10)  { atomicAdd(&acc[OFF_CNT + t], cL[t]); atomicAdd(&acc[OFF_ZSQ + t], qL[t]); }
    if (t < 100) atomicAdd(&acc[OFF_ZSUM + t], sL[t]);
    if (t == 0)  atomicAdd(&acc[OFF_KSUM + (blockIdx.x >= 16)], ks);
}

// ---------------- decoder + fused recon loss ----------------
// 16 rows/block, grid 512 (2 blocks/CU -> 2 waves/SIMD); 64-col chunks (wL 32KB, aT 8.5KB).
__global__ __launch_bounds__(256) void decoder_kernel(
    const float* __restrict__ wt_x, const float* __restrict__ ko_x,
    const float* __restrict__ Zb,
    const float* __restrict__ dw1, const float* __restrict__ db1,
    const float* __restrict__ dg,  const float* __restrict__ dbe,
    const float* __restrict__ dw2, const float* __restrict__ db2,
    float* __restrict__ acc)
{
    __shared__ float aT[128][17];    // [c][row], pad 17 -> conflict-free writes
    __shared__ float wL[128][64];
    __shared__ float rs[4];
    int t = threadIdx.x;
    int r0 = blockIdx.x * 16;
    const float* xbase = (r0 < 4096) ? wt_x : ko_x;
    int rloc = (r0 < 4096) ? r0 : r0 - 4096;

    {   // phase A: a = ReLU(LN(z @ dw1 + db1)) for 16 rows, 16 threads/row
        int lrow = t >> 4, tc = t & 15;
        const float* zr = Zb + (size_t)(r0 + lrow) * 10;
        float z[10];
#pragma unroll
        for (int d = 0; d < 10; ++d) z[d] = zr[d];
        float h[8];
#pragma unroll
        for (int i = 0; i < 8; ++i) {
            int c = tc + 16 * i;
            float a = db1[c];
#pragma unroll
            for (int d = 0; d < 10; ++d) a = fmaf(z[d], dw1[d * 128 + c], a);
            h[i] = a;
        }
        float s = 0.f;
#pragma unroll
        for (int i = 0; i < 8; ++i) s += h[i];
#pragma unroll
        for (int o = 8; o > 0; o >>= 1) s += __shfl_xor(s, o, 16);
        float m = s * (1.f / 128.f);
        float v = 0.f;
#pragma unroll
        for (int i = 0; i < 8; ++i) { float d_ = h[i] - m; v = fmaf(d_, d_, v); }
#pragma unroll
        for (int o = 8; o > 0; o >>= 1) v += __shfl_xor(v, o, 16);
        v *= (1.f / 128.f);
        float sc = 1.f / sqrtf(v + 1e-5f);
#pragma unroll
        for (int i = 0; i < 8; ++i) {
            int c = tc + 16 * i;
            aT[c][lrow] = fmaxf(fmaf((h[i] - m) * sc, dg[c], dbe[c]), 0.f);
        }
    }
    __syncthreads();

    int rg = t >> 5;    // 0..7 -> rows rg*2, rg*2+1
    int cg = t & 31;    // cols cg*2, cg*2+1 within chunk
    float rsum = 0.f;
    for (int cc2 = 0; cc2 < 32; ++cc2) {
        int j0 = cc2 * 64;
#pragma unroll
        for (int i = 0; i < 8; ++i) {
            int f = i * 256 + t;
            int c = f >> 4, q = f & 15;
            int j = j0 + q * 4;
            float4 w = (j < 2000) ? *(const float4*)(dw2 + (size_t)c * 2000 + j)
                                  : make_float4(0.f, 0.f, 0.f, 0.f);
            *(float4*)&wL[c][q * 4] = w;
        }
        __syncthreads();
        float d00 = 0.f, d01 = 0.f, d10 = 0.f, d11 = 0.f;
#pragma unroll 8
        for (int c = 0; c < 128; ++c) {
            float a0v = aT[c][rg * 2], a1v = aT[c][rg * 2 + 1];
            float2 w = *(const float2*)&wL[c][cg * 2];
            d00 = fmaf(a0v, w.x, d00); d01 = fmaf(a0v, w.y, d01);
            d10 = fmaf(a1v, w.x, d10); d11 = fmaf(a1v, w.y, d11);
        }
        int j = j0 + cg * 2;
        if (j < 2000) {
            float b0 = db2[j], b1 = db2[j + 1];
            int ra = rloc + rg * 2;
            float2 xa = *(const float2*)(xbase + (size_t)ra * 2000 + j);
            float2 xc = *(const float2*)(xbase + (size_t)(ra + 1) * 2000 + j);
            float e;
            e = d00 + b0 - xa.x; rsum = fmaf(e, e, rsum);
            e = d01 + b1 - xa.y; rsum = fmaf(e, e, rsum);
            e = d10 + b0 - xc.x; rsum = fmaf(e, e, rsum);
            e = d11 + b1 - xc.y; rsum = fmaf(e, e, rsum);
        }
        __syncthreads();
    }
#pragma unroll
    for (int o = 32; o > 0; o >>= 1) rsum += __shfl_xor(rsum, o, 64);
    if ((t & 63) == 0) rs[t >> 6] = rsum;
    __syncthreads();
    if (t == 0) atomicAdd(&acc[OFF_REC], rs[0] + rs[1] + rs[2] + rs[3]);
}

// ---------------- finalize ----------------
__global__ void finalize_kernel(const float* __restrict__ acc, float* __restrict__ out)
{
    float total = 0.f, nsh = 0.f;
    for (int c = 0; c < 10; ++c) {
        float nw = acc[OFF_NWT + c], nk = acc[OFF_NKO + c];
        if (nw > 0.5f && nk > 0.5f) {
            float l1 = acc[OFF_L1 + c] / nw;
            float l2 = acc[OFF_L2 + c] / nk;
            total += 0.5f * (l1 + l2);
            nsh += 1.f;
        }
    }
    float contrast = (nsh > 0.f) ? total / nsh : 0.f;
    float ap = 0.f, np_ = 0.f;
    for (int c = 0; c < 10; ++c) {
        float cn = acc[OFF_CNT + c];
        if (cn > 0.5f) {
            float mu2 = 0.f;
            for (int d = 0; d < 10; ++d) {
                float mm = acc[OFF_ZSUM + c * 10 + d] / cn;
                mu2 = fmaf(mm, mm, mu2);
            }
            ap += acc[OFF_ZSQ + c] / cn - mu2;
            np_ += 1.f;
        }
    }
    float align = (np_ > 0.f) ? ap / np_ : 0.f;
    float kl = 0.01f * (acc[OFF_KSUM + 0] + acc[OFF_KSUM + 1]) * (1.f / 4096.f);
    float recon = acc[OFF_REC] * (1.f / 8192000.f);
    out[0] = recon + kl + 1.0f * contrast + 0.5f * align;
}

extern "C" void kernel_launch(void* const* d_in, const int* in_sizes, int n_in,
                              void* d_out, int out_size, void* d_ws, size_t ws_size,
                              hipStream_t stream)
{
    const float* wt_x   = (const float*)d_in[0];
    const float* ko_x   = (const float*)d_in[1];
    const int*   wtl    = (const int*)d_in[2];
    const int*   kol    = (const int*)d_in[3];
    const float* enc_w1 = (const float*)d_in[4];
    const float* enc_b1 = (const float*)d_in[5];
    const float* enc_g  = (const float*)d_in[6];
    const float* enc_be = (const float*)d_in[7];
    const float* enc_w2 = (const float*)d_in[8];
    const float* enc_b2 = (const float*)d_in[9];
    const float* kap_w1 = (const float*)d_in[10];
    const float* kap_b1 = (const float*)d_in[11];
    const float* kap_g  = (const float*)d_in[12];
    const float* kap_be = (const float*)d_in[13];
    const float* kap_w2 = (const float*)d_in[14];
    const float* kap_b2 = (const float*)d_in[15];
    const float* dw1    = (const float*)d_in[16];
    const float* db1    = (const float*)d_in[17];
    const float* dg     = (const float*)d_in[18];
    const float* dbe    = (const float*)d_in[19];
    const float* dw2    = (const float*)d_in[20];
    const float* db2    = (const float*)d_in[21];

    float* ws  = (float*)d_ws;
    float* acc = ws;
    __bf16* WThi = (__bf16*)(ws + WT_OFF);
    __bf16* WTlo = (__bf16*)(ws + WTLO_OFF);
    float* Hb  = ws + H_OFF;
    float* Zb  = ws + Z_OFF;
    float* Kap = ws + KAP_OFF;

    hipMemsetAsync(acc, 0, ACC_FLOATS * sizeof(float), stream);
    pack_w_kernel<<<128, 256, 0, stream>>>(enc_w1, kap_w1, WThi, WTlo);
    counts_kernel<<<1, 1024, 0, stream>>>(wtl, kol, acc);
    gemm1_kernel<<<256, 512, 0, stream>>>(wt_x, ko_x, WThi, WTlo, Hb);
    stage2_kernel<<<8192, 128, 0, stream>>>(Hb, enc_b1, enc_g, enc_be, enc_w2, enc_b2,
                                            kap_b1, kap_g, kap_be, kap_w2, kap_b2, Zb, Kap);
    contrast_kernel<<<1024, 256, 0, stream>>>(Zb, wtl, Zb + 4096 * 10, kol, acc + OFF_NKO, acc + OFF_L1);
    contrast_kernel<<<1024, 256, 0, stream>>>(Zb + 4096 * 10, kol, Zb, wtl, acc + OFF_NWT, acc + OFF_L2);
    align_kernel<<<32, 256, 0, stream>>>(Zb, wtl, kol, Kap, acc);
    decoder_kernel<<<512, 256, 0, stream>>>(wt_x, ko_x, Zb, dw1, db1, dg, dbe, dw2, db2, acc);
    finalize_kernel<<<1, 1, 0, stream>>>(acc, (float*)d_out);
}

// Round 3
// 372.247 us; speedup vs baseline: 1.6946x; 1.6148x over previous
//
#include <hip/hip_runtime.h>
#include <math.h>

typedef __attribute__((ext_vector_type(8))) __bf16 bf16x8;
typedef __attribute__((ext_vector_type(4))) float f32x4;

// ---- workspace layout (float offsets) ----
#define OFF_NWT   0
#define OFF_NKO   10
#define OFF_L1    20
#define OFF_L2    30
#define OFF_CNT   40
#define OFF_ZSUM  50
#define OFF_ZSQ   150
#define OFF_KSUM  160
#define OFF_REC   162
#define ACC_FLOATS 192

#define WT_OFF    256                        // WThi [256][2048] bf16 = 262144 floats
#define WTLO_OFF  (WT_OFF + 262144)          // WTlo
#define H_OFF     (WTLO_OFF + 262144)        // H [8192][256] fp32 (enc 0-127 | kap 128-255)
#define Z_OFF     (H_OFF + 8192*256)         // Z [8192][10]
#define KAP_OFF   (Z_OFF + 8192*10)          // kappa [8192]

// ---------------- pack: transpose + bf16 hi/lo split of [enc_w1|kap_w1] ----------------
__global__ __launch_bounds__(256) void pack_w_kernel(const float* __restrict__ enc_w1,
                                                     const float* __restrict__ kap_w1,
                                                     __bf16* __restrict__ WThi,
                                                     __bf16* __restrict__ WTlo)
{
    __shared__ float tile[64][65];
    int kt = blockIdx.x & 31;
    int ct = blockIdx.x >> 5;
    int k0 = kt * 64, c0 = ct * 64;
    int t = threadIdx.x;
    int lr = t >> 6, lc = t & 63;
#pragma unroll
    for (int i = 0; i < 16; ++i) {
        int k = k0 + lr + 4 * i;
        int c = c0 + lc;
        float v = 0.f;
        if (k < 2000) v = (c < 128) ? enc_w1[(size_t)k * 128 + c]
                                    : kap_w1[(size_t)k * 128 + (c - 128)];
        tile[lc][lr + 4 * i] = v;
    }
    __syncthreads();
#pragma unroll
    for (int i = 0; i < 16; ++i) {
        int c = c0 + lr + 4 * i;
        int k = k0 + lc;
        float v = tile[lr + 4 * i][lc];
        __bf16 h = (__bf16)v;
        __bf16 l = (__bf16)(v - (float)h);
        size_t idx = (size_t)c * 2048 + k;
        WThi[idx] = h;
        WTlo[idx] = l;
    }
}

// ---------------- class counts ----------------
__global__ void counts_kernel(const int* __restrict__ wtl, const int* __restrict__ kol,
                              float* __restrict__ acc)
{
    __shared__ int cw[10], ck[10];
    int t = threadIdx.x;
    if (t < 10) { cw[t] = 0; ck[t] = 0; }
    __syncthreads();
    for (int i = t; i < 4096; i += 1024) {
        atomicAdd(&cw[wtl[i]], 1);
        atomicAdd(&ck[kol[i]], 1);
    }
    __syncthreads();
    if (t < 10) { acc[OFF_NWT + t] = (float)cw[t]; acc[OFF_NKO + t] = (float)ck[t]; }
}

// ---------------- GEMM1 (MFMA bf16x3): H[8192][256] = X[8192][2000] @ W[2000][256] ----------------
// BM=32, BN=256, BK=32, 512 thr (8 waves = 2m x 4n). All double-buffer registers STATICALLY
// named (rule #20: runtime-indexed ext_vector arrays spill to scratch — round 2's 623MB WRITE).
__global__ __launch_bounds__(512) void gemm1_kernel(const float* __restrict__ wt_x,
                                                    const float* __restrict__ ko_x,
                                                    const __bf16* __restrict__ WThi,
                                                    const __bf16* __restrict__ WTlo,
                                                    float* __restrict__ Hb)
{
    __shared__ short Bs[2][2][8192];   // [buf][hi/lo][unit*8 shorts] = 64 KB
    int t = threadIdx.x;
    int widx = t >> 6, lane = t & 63;
    int wm = widx >> 2, wn = widx & 3;
    int R0 = blockIdx.x * 32;
    const float* xb = (R0 < 4096) ? (wt_x + (size_t)R0 * 2000)
                                  : (ko_x + (size_t)(R0 - 4096) * 2000);
    int arow = wm * 16 + (lane & 15);
    const float* xrow = xb + (size_t)arow * 2000;
    int kboff = (lane >> 4) * 8;

    int cc0 = (t >> 2) & 15;
    int s0  = (t & 3) ^ ((cc0 >> 1) & 3);
    int col0 = (t >> 6) * 16 + cc0;
    size_t boff0 = (size_t)col0 * 2048 + s0 * 8;
    size_t boff1 = boff0 + (size_t)128 * 2048;

    f32x4 acc0, acc1, acc2, acc3;
#pragma unroll
    for (int r = 0; r < 4; ++r) { acc0[r] = 0.f; acc1[r] = 0.f; acc2[r] = 0.f; acc3[r] = 0.f; }

    uint4 bhA0, bhA1, blA0, blA1;      // B-staging set A (even steps)
    uint4 bhB0, bhB1, blB0, blB1;      // B-staging set B (odd steps)
    float4 aA0, aA1, aB0, aB1;         // A-staging sets

#define GLOADB_(step, h0, h1, l0, l1) do { \
    h0 = *(const uint4*)(WThi + boff0 + (size_t)(step) * 32); \
    h1 = *(const uint4*)(WThi + boff1 + (size_t)(step) * 32); \
    l0 = *(const uint4*)(WTlo + boff0 + (size_t)(step) * 32); \
    l1 = *(const uint4*)(WTlo + boff1 + (size_t)(step) * 32); } while (0)

#define DSWRITE_(buf, h0, h1, l0, l1) do { \
    *(uint4*)&Bs[buf][0][t * 8]        = h0; \
    *(uint4*)&Bs[buf][0][4096 + t * 8] = h1; \
    *(uint4*)&Bs[buf][1][t * 8]        = l0; \
    *(uint4*)&Bs[buf][1][4096 + t * 8] = l1; } while (0)

#define GLOADA_(step, a0, a1) do { \
    int k0_ = (step) * 32; \
    int k_ = k0_ + kboff; \
    if (k0_ <= 1952) { \
        a0 = *(const float4*)(xrow + k_); \
        a1 = *(const float4*)(xrow + k_ + 4); \
    } else { \
        float t_[8]; \
        _Pragma("unroll") \
        for (int j = 0; j < 8; ++j) { int kk = k_ + j; t_[j] = (kk < 2000) ? xrow[kk] : 0.f; } \
        a0 = make_float4(t_[0], t_[1], t_[2], t_[3]); \
        a1 = make_float4(t_[4], t_[5], t_[6], t_[7]); } } while (0)

#define CONVA_(a0, a1, ahi, alo) do { \
    float av_[8] = {a0.x, a0.y, a0.z, a0.w, a1.x, a1.y, a1.z, a1.w}; \
    _Pragma("unroll") \
    for (int j = 0; j < 8; ++j) { \
        __bf16 h_ = (__bf16)av_[j]; \
        ahi[j] = h_; \
        alo[j] = (__bf16)(av_[j] - (float)h_); } } while (0)

#define MFMA_(buf) do { \
    _Pragma("unroll") \
    for (int nf = 0; nf < 4; ++nf) { \
        bf16x8 bhf = *(const bf16x8*)&Bs[buf][0][(ubase + nf * 64) * 8]; \
        bf16x8 blf = *(const bf16x8*)&Bs[buf][1][(ubase + nf * 64) * 8]; \
        f32x4* ac = (nf == 0) ? &acc0 : (nf == 1) ? &acc1 : (nf == 2) ? &acc2 : &acc3; \
        *ac = __builtin_amdgcn_mfma_f32_16x16x32_bf16(ahi, bhf, *ac, 0, 0, 0); \
        *ac = __builtin_amdgcn_mfma_f32_16x16x32_bf16(alo, bhf, *ac, 0, 0, 0); \
        *ac = __builtin_amdgcn_mfma_f32_16x16x32_bf16(ahi, blf, *ac, 0, 0, 0); } } while (0)

    // prologue: steps 0 (set A) and 1 (set B) in flight; buf0 <- step 0
    GLOADB_(0, bhA0, bhA1, blA0, blA1); GLOADA_(0, aA0, aA1);
    GLOADB_(1, bhB0, bhB1, blB0, blB1); GLOADA_(1, aB0, aB1);
    DSWRITE_(0, bhA0, bhA1, blA0, blA1);
    __syncthreads();

    int cpr = lane & 15;
    int pph = (lane >> 4) ^ ((cpr >> 1) & 3);
    int ubase = (wn * 4) * 64 + cpr * 4 + pph;

    for (int it = 0; it < 32; ++it) {
        int st0 = it * 2;
        {   // even step st0: compute buf0 (holds step st0), set A holds A(st0)
            bf16x8 ahi, alo;
            CONVA_(aA0, aA1, ahi, alo);
            if (st0 + 2 < 64) { GLOADB_(st0 + 2, bhA0, bhA1, blA0, blA1); GLOADA_(st0 + 2, aA0, aA1); }
            DSWRITE_(1, bhB0, bhB1, blB0, blB1);          // step st0+1 -> buf1
            MFMA_(0);
            __syncthreads();
        }
        {   // odd step st0+1: compute buf1, set B holds A(st0+1)
            bf16x8 ahi, alo;
            CONVA_(aB0, aB1, ahi, alo);
            if (st0 + 3 < 64) { GLOADB_(st0 + 3, bhB0, bhB1, blB0, blB1); GLOADA_(st0 + 3, aB0, aB1); }
            if (st0 + 2 < 64) DSWRITE_(0, bhA0, bhA1, blA0, blA1);   // step st0+2 -> buf0
            MFMA_(1);
            __syncthreads();
        }
    }

    // epilogue: C/D layout col=lane&15, row=(lane>>4)*4+r  [m89-verified]
#pragma unroll
    for (int r = 0; r < 4; ++r) {
        int row = R0 + wm * 16 + (lane >> 4) * 4 + r;
        size_t base = (size_t)row * 256 + wn * 64 + (lane & 15);
        Hb[base]      = acc0[r];
        Hb[base + 16] = acc1[r];
        Hb[base + 32] = acc2[r];
        Hb[base + 48] = acc3[r];
    }
#undef GLOADB_
#undef DSWRITE_
#undef GLOADA_
#undef CONVA_
#undef MFMA_
}

// ---------------- stage2: LN->ReLU->head matmuls per row ----------------
__global__ __launch_bounds__(128) void stage2_kernel(const float* __restrict__ Hb,
    const float* __restrict__ enc_b1, const float* __restrict__ enc_g, const float* __restrict__ enc_be,
    const float* __restrict__ enc_w2, const float* __restrict__ enc_b2,
    const float* __restrict__ kap_b1, const float* __restrict__ kap_g, const float* __restrict__ kap_be,
    const float* __restrict__ kap_w2, const float* __restrict__ kap_b2,
    float* __restrict__ Z, float* __restrict__ Kap)
{
    __shared__ float sh[128];
    int row  = blockIdx.x;
    int wave = threadIdx.x >> 6;
    int lane = threadIdx.x & 63;
    const float* hb = Hb + (size_t)row * 256 + wave * 128;
    const float* b1 = wave ? kap_b1 : enc_b1;
    const float* gg = wave ? kap_g  : enc_g;
    const float* bb = wave ? kap_be : enc_be;

    float h0 = hb[lane]      + b1[lane];
    float h1 = hb[lane + 64] + b1[lane + 64];
    float s = h0 + h1;
#pragma unroll
    for (int o = 32; o > 0; o >>= 1) s += __shfl_xor(s, o, 64);
    float m = s * (1.f / 128.f);
    float d0 = h0 - m, d1 = h1 - m;
    float v = d0 * d0 + d1 * d1;
#pragma unroll
    for (int o = 32; o > 0; o >>= 1) v += __shfl_xor(v, o, 64);
    v *= (1.f / 128.f);
    float sc = 1.f / sqrtf(v + 1e-5f);
    float r0 = fmaxf(fmaf(d0 * sc, gg[lane],      bb[lane]),      0.f);
    float r1 = fmaxf(fmaf(d1 * sc, gg[lane + 64], bb[lane + 64]), 0.f);

    if (wave == 0) { sh[lane] = r0; sh[lane + 64] = r1; }
    __syncthreads();

    if (wave == 0) {
        float mu = 0.f;
        if (lane < 10) {
            mu = enc_b2[lane];
            for (int c = 0; c < 128; ++c) mu = fmaf(sh[c], enc_w2[c * 10 + lane], mu);
        }
        float n2 = mu * mu;
#pragma unroll
        for (int o = 8; o > 0; o >>= 1) n2 += __shfl_xor(n2, o, 16);
        float inv = 1.f / fmaxf(sqrtf(n2), 1e-12f);
        if (lane < 10) Z[(size_t)row * 10 + lane] = mu * inv;
    } else {
        float p = r0 * kap_w2[lane] + r1 * kap_w2[lane + 64];
#pragma unroll
        for (int o = 32; o > 0; o >>= 1) p += __shfl_xor(p, o, 64);
        if (lane == 0) {
            float x = p + kap_b2[0];
            float sp = (x > 20.f) ? x : log1pf(expf(x));
            Kap[row] = sp + 1e-6f;
        }
    }
}

// ---------------- contrastive pass (one wave per A-row) ----------------
__global__ __launch_bounds__(256) void contrast_kernel(const float* __restrict__ ZA,
                                                       const int* __restrict__ yA,
                                                       const float* __restrict__ ZB,
                                                       const int* __restrict__ yB,
                                                       const float* __restrict__ nB,
                                                       float* __restrict__ outc)
{
    int i    = blockIdx.x * 4 + (threadIdx.x >> 6);
    int lane = threadIdx.x & 63;
    int ci = yA[i];
    float nb = nB[ci];
    float za[10];
#pragma unroll
    for (int d = 0; d < 10; ++d) za[d] = ZA[(size_t)i * 10 + d];
    float se = 0.f, ss = 0.f;
    for (int j = lane; j < 4096; j += 64) {
        if (yB[j] == ci) {
            const float* zb = ZB + (size_t)j * 10;
            float s = 0.f;
#pragma unroll
            for (int d = 0; d < 10; ++d) s = fmaf(za[d], zb[d], s);
            s *= 10.f;                       // 1/TAU
            se += expf(s - 10.f);            // |S| <= 10
            ss += s;
        }
    }
#pragma unroll
    for (int o = 32; o > 0; o >>= 1) { se += __shfl_xor(se, o, 64); ss += __shfl_xor(ss, o, 64); }
    if (lane == 0 && nb > 0.5f) {
        float lse = 10.f + logf(se);
        atomicAdd(&outc[ci], lse - ss / nb);
    }
}

// ---------------- alignment stats + kappa reduction ----------------
__global__ __launch_bounds__(256) void align_kernel(const float* __restrict__ Z,
                                                    const int* __restrict__ wtl,
                                                    const int* __restrict__ kol,
                                                    const float* __restrict__ Kap,
                                                    float* __restrict__ acc)
{
    __shared__ float cL[10], qL[10], sL[100], ks;
    int t = threadIdx.x;
    if (t < 10) { cL[t] = 0.f; qL[t] = 0.f; }
    if (t < 100) sL[t] = 0.f;
    if (t == 0) ks = 0.f;
    __syncthreads();
    int row = blockIdx.x * 256 + t;
    int c = (row < 4096) ? wtl[row] : kol[row - 4096];
    float zz[10]; float q = 0.f;
#pragma unroll
    for (int d = 0; d < 10; ++d) { zz[d] = Z[(size_t)row * 10 + d]; q = fmaf(zz[d], zz[d], q); }
    atomicAdd(&cL[c], 1.f);
    atomicAdd(&qL[c], q);
#pragma unroll
    for (int d = 0; d < 10; ++d) atomicAdd(&sL[c * 10 + d], zz[d]);
    atomicAdd(&ks, Kap[row]);
    __syncthreads();
    if (t < 10)  { atomicAdd(&acc[OFF_CNT + t], cL[t]); atomicAdd(&acc[OFF_ZSQ + t], qL[t]); }
    if (t < 100) atomicAdd(&acc[OFF_ZSUM + t], sL[t]);
    if (t == 0)  atomicAdd(&acc[OFF_KSUM + (blockIdx.x >= 16)], ks);
}

// ---------------- decoder + fused recon loss ----------------
// 16 rows/block, grid 512 (2 blocks/CU); 128-col chunks; 2x4 micro-tile.
__global__ __launch_bounds__(256) void decoder_kernel(
    const float* __restrict__ wt_x, const float* __restrict__ ko_x,
    const float* __restrict__ Zb,
    const float* __restrict__ dw1, const float* __restrict__ db1,
    const float* __restrict__ dg,  const float* __restrict__ dbe,
    const float* __restrict__ dw2, const float* __restrict__ db2,
    float* __restrict__ acc)
{
    __shared__ float aT[128][18];    // [c][row], pad 18 keeps float2 alignment
    __shared__ float wL[128][128];   // 64 KB
    __shared__ float rs[4];
    int t = threadIdx.x;
    int r0 = blockIdx.x * 16;
    const float* xbase = (r0 < 4096) ? wt_x : ko_x;
    int rloc = (r0 < 4096) ? r0 : r0 - 4096;

    {   // phase A: a = ReLU(LN(z @ dw1 + db1)) for 16 rows, 16 threads/row
        int lrow = t >> 4, tc = t & 15;
        const float* zr = Zb + (size_t)(r0 + lrow) * 10;
        float z[10];
#pragma unroll
        for (int d = 0; d < 10; ++d) z[d] = zr[d];
        float h[8];
#pragma unroll
        for (int i = 0; i < 8; ++i) {
            int c = tc + 16 * i;
            float a = db1[c];
#pragma unroll
            for (int d = 0; d < 10; ++d) a = fmaf(z[d], dw1[d * 128 + c], a);
            h[i] = a;
        }
        float s = 0.f;
#pragma unroll
        for (int i = 0; i < 8; ++i) s += h[i];
#pragma unroll
        for (int o = 8; o > 0; o >>= 1) s += __shfl_xor(s, o, 16);
        float m = s * (1.f / 128.f);
        float v = 0.f;
#pragma unroll
        for (int i = 0; i < 8; ++i) { float d_ = h[i] - m; v = fmaf(d_, d_, v); }
#pragma unroll
        for (int o = 8; o > 0; o >>= 1) v += __shfl_xor(v, o, 16);
        v *= (1.f / 128.f);
        float sc = 1.f / sqrtf(v + 1e-5f);
#pragma unroll
        for (int i = 0; i < 8; ++i) {
            int c = tc + 16 * i;
            aT[c][lrow] = fmaxf(fmaf((h[i] - m) * sc, dg[c], dbe[c]), 0.f);
        }
    }
    __syncthreads();

    int rg = t >> 5;    // 0..7 -> rows rg*2, rg*2+1
    int cg = t & 31;    // cols cg*4..+3 within 128-col chunk
    float rsum = 0.f;
    for (int cc2 = 0; cc2 < 16; ++cc2) {
        int j0 = cc2 * 128;
#pragma unroll
        for (int i = 0; i < 16; ++i) {
            int f = i * 256 + t;
            int c = f >> 5, q = f & 31;
            int j = j0 + q * 4;
            float4 w = (j < 2000) ? *(const float4*)(dw2 + (size_t)c * 2000 + j)
                                  : make_float4(0.f, 0.f, 0.f, 0.f);
            *(float4*)&wL[c][q * 4] = w;
        }
        __syncthreads();
        float d00 = 0.f, d01 = 0.f, d02 = 0.f, d03 = 0.f;
        float d10 = 0.f, d11 = 0.f, d12 = 0.f, d13 = 0.f;
#pragma unroll 8
        for (int c = 0; c < 128; ++c) {
            float2 a2 = *(const float2*)&aT[c][rg * 2];
            float4 w4 = *(const float4*)&wL[c][cg * 4];
            d00 = fmaf(a2.x, w4.x, d00); d01 = fmaf(a2.x, w4.y, d01);
            d02 = fmaf(a2.x, w4.z, d02); d03 = fmaf(a2.x, w4.w, d03);
            d10 = fmaf(a2.y, w4.x, d10); d11 = fmaf(a2.y, w4.y, d11);
            d12 = fmaf(a2.y, w4.z, d12); d13 = fmaf(a2.y, w4.w, d13);
        }
        int j = j0 + cg * 4;
        if (j < 2000) {
            float4 b4 = *(const float4*)(db2 + j);
            int ra = rloc + rg * 2;
            float4 x0 = *(const float4*)(xbase + (size_t)ra * 2000 + j);
            float4 x1 = *(const float4*)(xbase + (size_t)(ra + 1) * 2000 + j);
            float e;
            e = d00 + b4.x - x0.x; rsum = fmaf(e, e, rsum);
            e = d01 + b4.y - x0.y; rsum = fmaf(e, e, rsum);
            e = d02 + b4.z - x0.z; rsum = fmaf(e, e, rsum);
            e = d03 + b4.w - x0.w; rsum = fmaf(e, e, rsum);
            e = d10 + b4.x - x1.x; rsum = fmaf(e, e, rsum);
            e = d11 + b4.y - x1.y; rsum = fmaf(e, e, rsum);
            e = d12 + b4.z - x1.z; rsum = fmaf(e, e, rsum);
            e = d13 + b4.w - x1.w; rsum = fmaf(e, e, rsum);
        }
        __syncthreads();
    }
#pragma unroll
    for (int o = 32; o > 0; o >>= 1) rsum += __shfl_xor(rsum, o, 64);
    if ((t & 63) == 0) rs[t >> 6] = rsum;
    __syncthreads();
    if (t == 0) atomicAdd(&acc[OFF_REC], rs[0] + rs[1] + rs[2] + rs[3]);
}

// ---------------- finalize ----------------
__global__ void finalize_kernel(const float* __restrict__ acc, float* __restrict__ out)
{
    float total = 0.f, nsh = 0.f;
    for (int c = 0; c < 10; ++c) {
        float nw = acc[OFF_NWT + c], nk = acc[OFF_NKO + c];
        if (nw > 0.5f && nk > 0.5f) {
            float l1 = acc[OFF_L1 + c] / nw;
            float l2 = acc[OFF_L2 + c] / nk;
            total += 0.5f * (l1 + l2);
            nsh += 1.f;
        }
    }
    float contrast = (nsh > 0.f) ? total / nsh : 0.f;
    float ap = 0.f, np_ = 0.f;
    for (int c = 0; c < 10; ++c) {
        float cn = acc[OFF_CNT + c];
        if (cn > 0.5f) {
            float mu2 = 0.f;
            for (int d = 0; d < 10; ++d) {
                float mm = acc[OFF_ZSUM + c * 10 + d] / cn;
                mu2 = fmaf(mm, mm, mu2);
            }
            ap += acc[OFF_ZSQ + c] / cn - mu2;
            np_ += 1.f;
        }
    }
    float align = (np_ > 0.f) ? ap / np_ : 0.f;
    float kl = 0.01f * (acc[OFF_KSUM + 0] + acc[OFF_KSUM + 1]) * (1.f / 4096.f);
    float recon = acc[OFF_REC] * (1.f / 8192000.f);
    out[0] = recon + kl + 1.0f * contrast + 0.5f * align;
}

extern "C" void kernel_launch(void* const* d_in, const int* in_sizes, int n_in,
                              void* d_out, int out_size, void* d_ws, size_t ws_size,
                              hipStream_t stream)
{
    const float* wt_x   = (const float*)d_in[0];
    const float* ko_x   = (const float*)d_in[1];
    const int*   wtl    = (const int*)d_in[2];
    const int*   kol    = (const int*)d_in[3];
    const float* enc_w1 = (const float*)d_in[4];
    const float* enc_b1 = (const float*)d_in[5];
    const float* enc_g  = (const float*)d_in[6];
    const float* enc_be = (const float*)d_in[7];
    const float* enc_w2 = (const float*)d_in[8];
    const float* enc_b2 = (const float*)d_in[9];
    const float* kap_w1 = (const float*)d_in[10];
    const float* kap_b1 = (const float*)d_in[11];
    const float* kap_g  = (const float*)d_in[12];
    const float* kap_be = (const float*)d_in[13];
    const float* kap_w2 = (const float*)d_in[14];
    const float* kap_b2 = (const float*)d_in[15];
    const float* dw1    = (const float*)d_in[16];
    const float* db1    = (const float*)d_in[17];
    const float* dg     = (const float*)d_in[18];
    const float* dbe    = (const float*)d_in[19];
    const float* dw2    = (const float*)d_in[20];
    const float* db2    = (const float*)d_in[21];

    float* ws  = (float*)d_ws;
    float* acc = ws;
    __bf16* WThi = (__bf16*)(ws + WT_OFF);
    __bf16* WTlo = (__bf16*)(ws + WTLO_OFF);
    float* Hb  = ws + H_OFF;
    float* Zb  = ws + Z_OFF;
    float* Kap = ws + KAP_OFF;

    hipMemsetAsync(acc, 0, ACC_FLOATS * sizeof(float), stream);
    pack_w_kernel<<<128, 256, 0, stream>>>(enc_w1, kap_w1, WThi, WTlo);
    counts_kernel<<<1, 1024, 0, stream>>>(wtl, kol, acc);
    gemm1_kernel<<<256, 512, 0, stream>>>(wt_x, ko_x, WThi, WTlo, Hb);
    stage2_kernel<<<8192, 128, 0, stream>>>(Hb, enc_b1, enc_g, enc_be, enc_w2, enc_b2,
                                            kap_b1, kap_g, kap_be, kap_w2, kap_b2, Zb, Kap);
    contrast_kernel<<<1024, 256, 0, stream>>>(Zb, wtl, Zb + 4096 * 10, kol, acc + OFF_NKO, acc + OFF_L1);
    contrast_kernel<<<1024, 256, 0, stream>>>(Zb + 4096 * 10, kol, Zb, wtl, acc + OFF_NWT, acc + OFF_L2);
    align_kernel<<<32, 256, 0, stream>>>(Zb, wtl, kol, Kap, acc);
    decoder_kernel<<<512, 256, 0, stream>>>(wt_x, ko_x, Zb, dw1, db1, dg, dbe, dw2, db2, acc);
    finalize_kernel<<<1, 1, 0, stream>>>(acc, (float*)d_out);
}

// Round 4
// 361.894 us; speedup vs baseline: 1.7431x; 1.0286x over previous
//
#include <hip/hip_runtime.h>
#include <math.h>

typedef __attribute__((ext_vector_type(8))) __bf16 bf16x8;
typedef __attribute__((ext_vector_type(4))) float f32x4;

// ---- workspace layout (float offsets) ----
#define OFF_NWT   0
#define OFF_NKO   10
#define OFF_L1    20
#define OFF_L2    30
#define OFF_CNT   40
#define OFF_ZSUM  50
#define OFF_ZSQ   150
#define OFF_KSUM  160
#define OFF_REC   162
#define ACC_FLOATS 192

#define WT_OFF    256                        // WThi [256][2048] bf16 = 262144 floats
#define WTLO_OFF  (WT_OFF + 262144)          // WTlo
#define H_OFF     (WTLO_OFF + 262144)        // H [8192][256] fp32 (enc | kap) -- dead after stage2
#define Z_OFF     (H_OFF + 8192*256)         // Z [8192][10]
#define KAP_OFF   (Z_OFF + 8192*10)          // kappa [8192]

// overlays on the dead H region (written only after stage2 consumed H):
#define ACT_HI_OFF  H_OFF                    // Act_hi [8192][128] bf16 = 524288 floats
#define ACT_LO_OFF  (H_OFF + 524288)
#define BT_HI_OFF   (H_OFF + 1048576)        // BT_hi [2048][128] bf16 = 131072 floats
#define BT_LO_OFF   (H_OFF + 1179648)        // ends H_OFF+1310720 < H_OFF+2097152

// ---------------- pack: transpose + bf16 hi/lo split of [enc_w1|kap_w1] ----------------
__global__ __launch_bounds__(256) void pack_w_kernel(const float* __restrict__ enc_w1,
                                                     const float* __restrict__ kap_w1,
                                                     __bf16* __restrict__ WThi,
                                                     __bf16* __restrict__ WTlo)
{
    __shared__ float tile[64][65];
    int kt = blockIdx.x & 31;
    int ct = blockIdx.x >> 5;
    int k0 = kt * 64, c0 = ct * 64;
    int t = threadIdx.x;
    int lr = t >> 6, lc = t & 63;
#pragma unroll
    for (int i = 0; i < 16; ++i) {
        int k = k0 + lr + 4 * i;
        int c = c0 + lc;
        float v = 0.f;
        if (k < 2000) v = (c < 128) ? enc_w1[(size_t)k * 128 + c]
                                    : kap_w1[(size_t)k * 128 + (c - 128)];
        tile[lc][lr + 4 * i] = v;
    }
    __syncthreads();
#pragma unroll
    for (int i = 0; i < 16; ++i) {
        int c = c0 + lr + 4 * i;
        int k = k0 + lc;
        float v = tile[lr + 4 * i][lc];
        __bf16 h = (__bf16)v;
        __bf16 l = (__bf16)(v - (float)h);
        size_t idx = (size_t)c * 2048 + k;
        WThi[idx] = h;
        WTlo[idx] = l;
    }
}

// ---------------- pack: transpose + bf16 hi/lo split of dec_w2 [128][2000] -> BT [2048][128] ----
__global__ __launch_bounds__(256) void pack_dw2_kernel(const float* __restrict__ dw2,
                                                       __bf16* __restrict__ BThi,
                                                       __bf16* __restrict__ BTlo)
{
    __shared__ float tile[64][129];   // [jj][c]
    int j0 = blockIdx.x * 64;
    int t = threadIdx.x;
#pragma unroll
    for (int i = 0; i < 32; ++i) {
        int idx = i * 256 + t;
        int c = idx >> 6, jj = idx & 63;
        int j = j0 + jj;
        tile[jj][c] = (j < 2000) ? dw2[(size_t)c * 2000 + j] : 0.f;
    }
    __syncthreads();
#pragma unroll
    for (int i = 0; i < 32; ++i) {
        int idx = i * 256 + t;
        int jj = idx >> 7, c = idx & 127;
        float v = tile[jj][c];
        __bf16 h = (__bf16)v;
        size_t o = (size_t)(j0 + jj) * 128 + c;
        BThi[o] = h;
        BTlo[o] = (__bf16)(v - (float)h);
    }
}

// ---------------- class counts ----------------
__global__ void counts_kernel(const int* __restrict__ wtl, const int* __restrict__ kol,
                              float* __restrict__ acc)
{
    __shared__ int cw[10], ck[10];
    int t = threadIdx.x;
    if (t < 10) { cw[t] = 0; ck[t] = 0; }
    __syncthreads();
    for (int i = t; i < 4096; i += 1024) {
        atomicAdd(&cw[wtl[i]], 1);
        atomicAdd(&ck[kol[i]], 1);
    }
    __syncthreads();
    if (t < 10) { acc[OFF_NWT + t] = (float)cw[t]; acc[OFF_NKO + t] = (float)ck[t]; }
}

// ---------------- GEMM1 (MFMA bf16x3): H[8192][256] = X[8192][2000] @ W[2000][256] ----------------
__global__ __launch_bounds__(512) void gemm1_kernel(const float* __restrict__ wt_x,
                                                    const float* __restrict__ ko_x,
                                                    const __bf16* __restrict__ WThi,
                                                    const __bf16* __restrict__ WTlo,
                                                    float* __restrict__ Hb)
{
    __shared__ short Bs[2][2][8192];   // [buf][hi/lo][unit*8 shorts] = 64 KB
    int t = threadIdx.x;
    int widx = t >> 6, lane = t & 63;
    int wm = widx >> 2, wn = widx & 3;
    int R0 = blockIdx.x * 32;
    const float* xb = (R0 < 4096) ? (wt_x + (size_t)R0 * 2000)
                                  : (ko_x + (size_t)(R0 - 4096) * 2000);
    int arow = wm * 16 + (lane & 15);
    const float* xrow = xb + (size_t)arow * 2000;
    int kboff = (lane >> 4) * 8;

    int cc0 = (t >> 2) & 15;
    int s0  = (t & 3) ^ ((cc0 >> 1) & 3);
    int col0 = (t >> 6) * 16 + cc0;
    size_t boff0 = (size_t)col0 * 2048 + s0 * 8;
    size_t boff1 = boff0 + (size_t)128 * 2048;

    f32x4 acc0, acc1, acc2, acc3;
#pragma unroll
    for (int r = 0; r < 4; ++r) { acc0[r] = 0.f; acc1[r] = 0.f; acc2[r] = 0.f; acc3[r] = 0.f; }

    uint4 bhA0, bhA1, blA0, blA1;
    uint4 bhB0, bhB1, blB0, blB1;
    float4 aA0, aA1, aB0, aB1;

#define GLOADB_(step, h0, h1, l0, l1) do { \
    h0 = *(const uint4*)(WThi + boff0 + (size_t)(step) * 32); \
    h1 = *(const uint4*)(WThi + boff1 + (size_t)(step) * 32); \
    l0 = *(const uint4*)(WTlo + boff0 + (size_t)(step) * 32); \
    l1 = *(const uint4*)(WTlo + boff1 + (size_t)(step) * 32); } while (0)

#define DSWRITE_(buf, h0, h1, l0, l1) do { \
    *(uint4*)&Bs[buf][0][t * 8]        = h0; \
    *(uint4*)&Bs[buf][0][4096 + t * 8] = h1; \
    *(uint4*)&Bs[buf][1][t * 8]        = l0; \
    *(uint4*)&Bs[buf][1][4096 + t * 8] = l1; } while (0)

#define GLOADA_(step, a0, a1) do { \
    int k0_ = (step) * 32; \
    int k_ = k0_ + kboff; \
    if (k0_ <= 1952) { \
        a0 = *(const float4*)(xrow + k_); \
        a1 = *(const float4*)(xrow + k_ + 4); \
    } else { \
        float t_[8]; \
        _Pragma("unroll") \
        for (int j = 0; j < 8; ++j) { int kk = k_ + j; t_[j] = (kk < 2000) ? xrow[kk] : 0.f; } \
        a0 = make_float4(t_[0], t_[1], t_[2], t_[3]); \
        a1 = make_float4(t_[4], t_[5], t_[6], t_[7]); } } while (0)

#define CONVA_(a0, a1, ahi, alo) do { \
    float av_[8] = {a0.x, a0.y, a0.z, a0.w, a1.x, a1.y, a1.z, a1.w}; \
    _Pragma("unroll") \
    for (int j = 0; j < 8; ++j) { \
        __bf16 h_ = (__bf16)av_[j]; \
        ahi[j] = h_; \
        alo[j] = (__bf16)(av_[j] - (float)h_); } } while (0)

#define MFMA_(buf) do { \
    _Pragma("unroll") \
    for (int nf = 0; nf < 4; ++nf) { \
        bf16x8 bhf = *(const bf16x8*)&Bs[buf][0][(ubase + nf * 64) * 8]; \
        bf16x8 blf = *(const bf16x8*)&Bs[buf][1][(ubase + nf * 64) * 8]; \
        f32x4* ac = (nf == 0) ? &acc0 : (nf == 1) ? &acc1 : (nf == 2) ? &acc2 : &acc3; \
        *ac = __builtin_amdgcn_mfma_f32_16x16x32_bf16(ahi, bhf, *ac, 0, 0, 0); \
        *ac = __builtin_amdgcn_mfma_f32_16x16x32_bf16(alo, bhf, *ac, 0, 0, 0); \
        *ac = __builtin_amdgcn_mfma_f32_16x16x32_bf16(ahi, blf, *ac, 0, 0, 0); } } while (0)

    GLOADB_(0, bhA0, bhA1, blA0, blA1); GLOADA_(0, aA0, aA1);
    GLOADB_(1, bhB0, bhB1, blB0, blB1); GLOADA_(1, aB0, aB1);
    DSWRITE_(0, bhA0, bhA1, blA0, blA1);
    __syncthreads();

    int cpr = lane & 15;
    int pph = (lane >> 4) ^ ((cpr >> 1) & 3);
    int ubase = (wn * 4) * 64 + cpr * 4 + pph;

    for (int it = 0; it < 32; ++it) {
        int st0 = it * 2;
        {
            bf16x8 ahi, alo;
            CONVA_(aA0, aA1, ahi, alo);
            if (st0 + 2 < 64) { GLOADB_(st0 + 2, bhA0, bhA1, blA0, blA1); GLOADA_(st0 + 2, aA0, aA1); }
            DSWRITE_(1, bhB0, bhB1, blB0, blB1);
            MFMA_(0);
            __syncthreads();
        }
        {
            bf16x8 ahi, alo;
            CONVA_(aB0, aB1, ahi, alo);
            if (st0 + 3 < 64) { GLOADB_(st0 + 3, bhB0, bhB1, blB0, blB1); GLOADA_(st0 + 3, aB0, aB1); }
            if (st0 + 2 < 64) DSWRITE_(0, bhA0, bhA1, blA0, blA1);
            MFMA_(1);
            __syncthreads();
        }
    }

#pragma unroll
    for (int r = 0; r < 4; ++r) {
        int row = R0 + wm * 16 + (lane >> 4) * 4 + r;
        size_t base = (size_t)row * 256 + wn * 64 + (lane & 15);
        Hb[base]      = acc0[r];
        Hb[base + 16] = acc1[r];
        Hb[base + 32] = acc2[r];
        Hb[base + 48] = acc3[r];
    }
#undef GLOADB_
#undef DSWRITE_
#undef GLOADA_
#undef CONVA_
#undef MFMA_
}

// ---------------- stage2: LN->ReLU->head matmuls per row ----------------
__global__ __launch_bounds__(128) void stage2_kernel(const float* __restrict__ Hb,
    const float* __restrict__ enc_b1, const float* __restrict__ enc_g, const float* __restrict__ enc_be,
    const float* __restrict__ enc_w2, const float* __restrict__ enc_b2,
    const float* __restrict__ kap_b1, const float* __restrict__ kap_g, const float* __restrict__ kap_be,
    const float* __restrict__ kap_w2, const float* __restrict__ kap_b2,
    float* __restrict__ Z, float* __restrict__ Kap)
{
    __shared__ float sh[128];
    int row  = blockIdx.x;
    int wave = threadIdx.x >> 6;
    int lane = threadIdx.x & 63;
    const float* hb = Hb + (size_t)row * 256 + wave * 128;
    const float* b1 = wave ? kap_b1 : enc_b1;
    const float* gg = wave ? kap_g  : enc_g;
    const float* bb = wave ? kap_be : enc_be;

    float h0 = hb[lane]      + b1[lane];
    float h1 = hb[lane + 64] + b1[lane + 64];
    float s = h0 + h1;
#pragma unroll
    for (int o = 32; o > 0; o >>= 1) s += __shfl_xor(s, o, 64);
    float m = s * (1.f / 128.f);
    float d0 = h0 - m, d1 = h1 - m;
    float v = d0 * d0 + d1 * d1;
#pragma unroll
    for (int o = 32; o > 0; o >>= 1) v += __shfl_xor(v, o, 64);
    v *= (1.f / 128.f);
    float sc = 1.f / sqrtf(v + 1e-5f);
    float r0 = fmaxf(fmaf(d0 * sc, gg[lane],      bb[lane]),      0.f);
    float r1 = fmaxf(fmaf(d1 * sc, gg[lane + 64], bb[lane + 64]), 0.f);

    if (wave == 0) { sh[lane] = r0; sh[lane + 64] = r1; }
    __syncthreads();

    if (wave == 0) {
        float mu = 0.f;
        if (lane < 10) {
            mu = enc_b2[lane];
            for (int c = 0; c < 128; ++c) mu = fmaf(sh[c], enc_w2[c * 10 + lane], mu);
        }
        float n2 = mu * mu;
#pragma unroll
        for (int o = 8; o > 0; o >>= 1) n2 += __shfl_xor(n2, o, 16);
        float inv = 1.f / fmaxf(sqrtf(n2), 1e-12f);
        if (lane < 10) Z[(size_t)row * 10 + lane] = mu * inv;
    } else {
        float p = r0 * kap_w2[lane] + r1 * kap_w2[lane + 64];
#pragma unroll
        for (int o = 32; o > 0; o >>= 1) p += __shfl_xor(p, o, 64);
        if (lane == 0) {
            float x = p + kap_b2[0];
            float sp = (x > 20.f) ? x : log1pf(expf(x));
            Kap[row] = sp + 1e-6f;
        }
    }
}

// ---------------- dec_act: a = ReLU(LN(z @ dw1 + db1)) -> bf16 hi/lo [8192][128] ----------------
__global__ __launch_bounds__(256) void dec_act_kernel(const float* __restrict__ Zb,
    const float* __restrict__ dw1, const float* __restrict__ db1,
    const float* __restrict__ dg,  const float* __restrict__ dbe,
    __bf16* __restrict__ Ahi, __bf16* __restrict__ Alo)
{
    int wave = threadIdx.x >> 6;
    int lane = threadIdx.x & 63;
    int row = blockIdx.x * 4 + wave;
    const float* zr = Zb + (size_t)row * 10;
    float z[10];
#pragma unroll
    for (int d = 0; d < 10; ++d) z[d] = zr[d];
    int c0 = lane, c1 = lane + 64;
    float h0 = db1[c0], h1 = db1[c1];
#pragma unroll
    for (int d = 0; d < 10; ++d) {
        h0 = fmaf(z[d], dw1[d * 128 + c0], h0);
        h1 = fmaf(z[d], dw1[d * 128 + c1], h1);
    }
    float s = h0 + h1;
#pragma unroll
    for (int o = 32; o > 0; o >>= 1) s += __shfl_xor(s, o, 64);
    float m = s * (1.f / 128.f);
    float d0 = h0 - m, d1 = h1 - m;
    float v = d0 * d0 + d1 * d1;
#pragma unroll
    for (int o = 32; o > 0; o >>= 1) v += __shfl_xor(v, o, 64);
    v *= (1.f / 128.f);
    float sc = 1.f / sqrtf(v + 1e-5f);
    float a0 = fmaxf(fmaf(d0 * sc, dg[c0], dbe[c0]), 0.f);
    float a1 = fmaxf(fmaf(d1 * sc, dg[c1], dbe[c1]), 0.f);
    __bf16 h0b = (__bf16)a0, h1b = (__bf16)a1;
    size_t base = (size_t)row * 128;
    Ahi[base + c0] = h0b;                 Ahi[base + c1] = h1b;
    Alo[base + c0] = (__bf16)(a0 - (float)h0b);
    Alo[base + c1] = (__bf16)(a1 - (float)h1b);
}

// ---------------- dec_gemm: rec = Act @ dw2 + b2, fused sq-err vs x (MFMA bf16x3) ----------------
// grid 256 x 512 thr: 8 waves (2m x 4n); per block 32 rows; N swept in 32 iters of 64 cols.
__global__ __launch_bounds__(512) void dec_gemm_kernel(
    const __bf16* __restrict__ Ahi, const __bf16* __restrict__ Alo,
    const __bf16* __restrict__ BThi, const __bf16* __restrict__ BTlo,
    const float* __restrict__ wt_x, const float* __restrict__ ko_x,
    const float* __restrict__ db2, float* __restrict__ acc)
{
    __shared__ float rs[8];
    int t = threadIdx.x;
    int widx = t >> 6, lane = t & 63;
    int wm = widx >> 2, wn = widx & 3;
    int R0 = blockIdx.x * 32;
    const float* xbase = (R0 < 4096) ? wt_x : ko_x;
    int xr0 = ((R0 < 4096) ? R0 : R0 - 4096) + wm * 16 + (lane >> 4) * 4;

    // A-fragments: row = lane&15 within the wave's 16-row panel, k = (lane>>4)*8 + j
    size_t abase = (size_t)(R0 + wm * 16 + (lane & 15)) * 128 + (lane >> 4) * 8;
    bf16x8 ah0 = *(const bf16x8*)(Ahi + abase);
    bf16x8 ah1 = *(const bf16x8*)(Ahi + abase + 32);
    bf16x8 ah2 = *(const bf16x8*)(Ahi + abase + 64);
    bf16x8 ah3 = *(const bf16x8*)(Ahi + abase + 96);
    bf16x8 al0 = *(const bf16x8*)(Alo + abase);
    bf16x8 al1 = *(const bf16x8*)(Alo + abase + 32);
    bf16x8 al2 = *(const bf16x8*)(Alo + abase + 64);
    bf16x8 al3 = *(const bf16x8*)(Alo + abase + 96);

    float rsum = 0.f;
    for (int itn = 0; itn < 32; ++itn) {
        int col = itn * 64 + wn * 16 + (lane & 15);
        size_t bbase = (size_t)col * 128 + (lane >> 4) * 8;
        bf16x8 bh0 = *(const bf16x8*)(BThi + bbase);
        bf16x8 bh1 = *(const bf16x8*)(BThi + bbase + 32);
        bf16x8 bh2 = *(const bf16x8*)(BThi + bbase + 64);
        bf16x8 bh3 = *(const bf16x8*)(BThi + bbase + 96);
        bf16x8 bl0 = *(const bf16x8*)(BTlo + bbase);
        bf16x8 bl1 = *(const bf16x8*)(BTlo + bbase + 32);
        bf16x8 bl2 = *(const bf16x8*)(BTlo + bbase + 64);
        bf16x8 bl3 = *(const bf16x8*)(BTlo + bbase + 96);

        f32x4 a4;
#pragma unroll
        for (int r = 0; r < 4; ++r) a4[r] = 0.f;
        a4 = __builtin_amdgcn_mfma_f32_16x16x32_bf16(ah0, bh0, a4, 0, 0, 0);
        a4 = __builtin_amdgcn_mfma_f32_16x16x32_bf16(al0, bh0, a4, 0, 0, 0);
        a4 = __builtin_amdgcn_mfma_f32_16x16x32_bf16(ah0, bl0, a4, 0, 0, 0);
        a4 = __builtin_amdgcn_mfma_f32_16x16x32_bf16(ah1, bh1, a4, 0, 0, 0);
        a4 = __builtin_amdgcn_mfma_f32_16x16x32_bf16(al1, bh1, a4, 0, 0, 0);
        a4 = __builtin_amdgcn_mfma_f32_16x16x32_bf16(ah1, bl1, a4, 0, 0, 0);
        a4 = __builtin_amdgcn_mfma_f32_16x16x32_bf16(ah2, bh2, a4, 0, 0, 0);
        a4 = __builtin_amdgcn_mfma_f32_16x16x32_bf16(al2, bh2, a4, 0, 0, 0);
        a4 = __builtin_amdgcn_mfma_f32_16x16x32_bf16(ah2, bl2, a4, 0, 0, 0);
        a4 = __builtin_amdgcn_mfma_f32_16x16x32_bf16(ah3, bh3, a4, 0, 0, 0);
        a4 = __builtin_amdgcn_mfma_f32_16x16x32_bf16(al3, bh3, a4, 0, 0, 0);
        a4 = __builtin_amdgcn_mfma_f32_16x16x32_bf16(ah3, bl3, a4, 0, 0, 0);

        if (col < 2000) {
            float bb = db2[col];
#pragma unroll
            for (int r = 0; r < 4; ++r) {
                float xv = xbase[(size_t)(xr0 + r) * 2000 + col];
                float e = a4[r] + bb - xv;
                rsum = fmaf(e, e, rsum);
            }
        }
    }
#pragma unroll
    for (int o = 32; o > 0; o >>= 1) rsum += __shfl_xor(rsum, o, 64);
    if (lane == 0) rs[widx] = rsum;
    __syncthreads();
    if (t == 0) {
        float s = 0.f;
#pragma unroll
        for (int w = 0; w < 8; ++w) s += rs[w];
        atomicAdd(&acc[OFF_REC], s);
    }
}

// ---------------- contrastive pass (one wave per A-row) ----------------
__global__ __launch_bounds__(256) void contrast_kernel(const float* __restrict__ ZA,
                                                       const int* __restrict__ yA,
                                                       const float* __restrict__ ZB,
                                                       const int* __restrict__ yB,
                                                       const float* __restrict__ nB,
                                                       float* __restrict__ outc)
{
    int i    = blockIdx.x * 4 + (threadIdx.x >> 6);
    int lane = threadIdx.x & 63;
    int ci = yA[i];
    float nb = nB[ci];
    float za[10];
#pragma unroll
    for (int d = 0; d < 10; ++d) za[d] = ZA[(size_t)i * 10 + d];
    float se = 0.f, ss = 0.f;
    for (int j = lane; j < 4096; j += 64) {
        if (yB[j] == ci) {
            const float* zb = ZB + (size_t)j * 10;
            float s = 0.f;
#pragma unroll
            for (int d = 0; d < 10; ++d) s = fmaf(za[d], zb[d], s);
            s *= 10.f;                       // 1/TAU
            se += expf(s - 10.f);            // |S| <= 10
            ss += s;
        }
    }
#pragma unroll
    for (int o = 32; o > 0; o >>= 1) { se += __shfl_xor(se, o, 64); ss += __shfl_xor(ss, o, 64); }
    if (lane == 0 && nb > 0.5f) {
        float lse = 10.f + logf(se);
        atomicAdd(&outc[ci], lse - ss / nb);
    }
}

// ---------------- alignment stats + kappa reduction ----------------
__global__ __launch_bounds__(256) void align_kernel(const float* __restrict__ Z,
                                                    const int* __restrict__ wtl,
                                                    const int* __restrict__ kol,
                                                    const float* __restrict__ Kap,
                                                    float* __restrict__ acc)
{
    __shared__ float cL[10], qL[10], sL[100], ks;
    int t = threadIdx.x;
    if (t < 10) { cL[t] = 0.f; qL[t] = 0.f; }
    if (t < 100) sL[t] = 0.f;
    if (t == 0) ks = 0.f;
    __syncthreads();
    int row = blockIdx.x * 256 + t;
    int c = (row < 4096) ? wtl[row] : kol[row - 4096];
    float zz[10]; float q = 0.f;
#pragma unroll
    for (int d = 0; d < 10; ++d) { zz[d] = Z[(size_t)row * 10 + d]; q = fmaf(zz[d], zz[d], q); }
    atomicAdd(&cL[c], 1.f);
    atomicAdd(&qL[c], q);
#pragma unroll
    for (int d = 0; d < 10; ++d) atomicAdd(&sL[c * 10 + d], zz[d]);
    atomicAdd(&ks, Kap[row]);
    __syncthreads();
    if (t < 10)  { atomicAdd(&acc[OFF_CNT + t], cL[t]); atomicAdd(&acc[OFF_ZSQ + t], qL[t]); }
    if (t < 100) atomicAdd(&acc[OFF_ZSUM + t], sL[t]);
    if (t == 0)  atomicAdd(&acc[OFF_KSUM + (blockIdx.x >= 16)], ks);
}

// ---------------- finalize ----------------
__global__ void finalize_kernel(const float* __restrict__ acc, float* __restrict__ out)
{
    float total = 0.f, nsh = 0.f;
    for (int c = 0; c < 10; ++c) {
        float nw = acc[OFF_NWT + c], nk = acc[OFF_NKO + c];
        if (nw > 0.5f && nk > 0.5f) {
            float l1 = acc[OFF_L1 + c] / nw;
            float l2 = acc[OFF_L2 + c] / nk;
            total += 0.5f * (l1 + l2);
            nsh += 1.f;
        }
    }
    float contrast = (nsh > 0.f) ? total / nsh : 0.f;
    float ap = 0.f, np_ = 0.f;
    for (int c = 0; c < 10; ++c) {
        float cn = acc[OFF_CNT + c];
        if (cn > 0.5f) {
            float mu2 = 0.f;
            for (int d = 0; d < 10; ++d) {
                float mm = acc[OFF_ZSUM + c * 10 + d] / cn;
                mu2 = fmaf(mm, mm, mu2);
            }
            ap += acc[OFF_ZSQ + c] / cn - mu2;
            np_ += 1.f;
        }
    }
    float align = (np_ > 0.f) ? ap / np_ : 0.f;
    float kl = 0.01f * (acc[OFF_KSUM + 0] + acc[OFF_KSUM + 1]) * (1.f / 4096.f);
    float recon = acc[OFF_REC] * (1.f / 8192000.f);
    out[0] = recon + kl + 1.0f * contrast + 0.5f * align;
}

extern "C" void kernel_launch(void* const* d_in, const int* in_sizes, int n_in,
                              void* d_out, int out_size, void* d_ws, size_t ws_size,
                              hipStream_t stream)
{
    const float* wt_x   = (const float*)d_in[0];
    const float* ko_x   = (const float*)d_in[1];
    const int*   wtl    = (const int*)d_in[2];
    const int*   kol    = (const int*)d_in[3];
    const float* enc_w1 = (const float*)d_in[4];
    const float* enc_b1 = (const float*)d_in[5];
    const float* enc_g  = (const float*)d_in[6];
    const float* enc_be = (const float*)d_in[7];
    const float* enc_w2 = (const float*)d_in[8];
    const float* enc_b2 = (const float*)d_in[9];
    const float* kap_w1 = (const float*)d_in[10];
    const float* kap_b1 = (const float*)d_in[11];
    const float* kap_g  = (const float*)d_in[12];
    const float* kap_be = (const float*)d_in[13];
    const float* kap_w2 = (const float*)d_in[14];
    const float* kap_b2 = (const float*)d_in[15];
    const float* dw1    = (const float*)d_in[16];
    const float* db1    = (const float*)d_in[17];
    const float* dg     = (const float*)d_in[18];
    const float* dbe    = (const float*)d_in[19];
    const float* dw2    = (const float*)d_in[20];
    const float* db2    = (const float*)d_in[21];

    float* ws  = (float*)d_ws;
    float* acc = ws;
    __bf16* WThi = (__bf16*)(ws + WT_OFF);
    __bf16* WTlo = (__bf16*)(ws + WTLO_OFF);
    float* Hb  = ws + H_OFF;
    float* Zb  = ws + Z_OFF;
    float* Kap = ws + KAP_OFF;
    __bf16* Ahi  = (__bf16*)(ws + ACT_HI_OFF);
    __bf16* Alo  = (__bf16*)(ws + ACT_LO_OFF);
    __bf16* BThi = (__bf16*)(ws + BT_HI_OFF);
    __bf16* BTlo = (__bf16*)(ws + BT_LO_OFF);

    hipMemsetAsync(acc, 0, ACC_FLOATS * sizeof(float), stream);
    pack_w_kernel<<<128, 256, 0, stream>>>(enc_w1, kap_w1, WThi, WTlo);
    counts_kernel<<<1, 1024, 0, stream>>>(wtl, kol, acc);
    gemm1_kernel<<<256, 512, 0, stream>>>(wt_x, ko_x, WThi, WTlo, Hb);
    stage2_kernel<<<8192, 128, 0, stream>>>(Hb, enc_b1, enc_g, enc_be, enc_w2, enc_b2,
                                            kap_b1, kap_g, kap_be, kap_w2, kap_b2, Zb, Kap);
    // H is dead from here; Act/BT overlay it
    pack_dw2_kernel<<<32, 256, 0, stream>>>(dw2, BThi, BTlo);
    dec_act_kernel<<<2048, 256, 0, stream>>>(Zb, dw1, db1, dg, dbe, Ahi, Alo);
    contrast_kernel<<<1024, 256, 0, stream>>>(Zb, wtl, Zb + 4096 * 10, kol, acc + OFF_NKO, acc + OFF_L1);
    contrast_kernel<<<1024, 256, 0, stream>>>(Zb + 4096 * 10, kol, Zb, wtl, acc + OFF_NWT, acc + OFF_L2);
    align_kernel<<<32, 256, 0, stream>>>(Zb, wtl, kol, Kap, acc);
    dec_gemm_kernel<<<256, 512, 0, stream>>>(Ahi, Alo, BThi, BTlo, wt_x, ko_x, db2, acc);
    finalize_kernel<<<1, 1, 0, stream>>>(acc, (float*)d_out);
}

// Round 5
// 305.740 us; speedup vs baseline: 2.0632x; 1.1837x over previous
//
#include <hip/hip_runtime.h>
#include <math.h>

typedef __attribute__((ext_vector_type(8))) __bf16 bf16x8;
typedef __attribute__((ext_vector_type(4))) float f32x4;

// ---- workspace layout (float offsets) ----
#define OFF_NWT   0
#define OFF_NKO   10
#define OFF_L1    20
#define OFF_L2    30
#define OFF_CNT   40
#define OFF_ZSUM  50
#define OFF_ZSQ   150
#define OFF_KSUM  160
#define OFF_REC   162
// int-typed slots (indices into the same float array, viewed as int*)
#define IOFF_WTOFF 192      // int wtOff[11]
#define IOFF_KOOFF 204      // int koOff[11]
#define IOFF_WTCTR 216      // int wtCtr[10]
#define IOFF_KOCTR 226      // int koCtr[10]
#define ACC_FLOATS 256

#define WT_OFF    256                        // WThi [256][2048] bf16 = 262144 floats
#define WTLO_OFF  (WT_OFF + 262144)          // WTlo
#define H_OFF     (WTLO_OFF + 262144)        // H [8192][256] fp32 (enc | kap) -- dead after stage2
#define Z_OFF     (H_OFF + 8192*256)         // Z [8192][10]
#define KAP_OFF   (Z_OFF + 8192*10)          // kappa [8192]

// overlays on the dead H region (written only after stage2 consumed H):
#define ACT_HI_OFF  H_OFF                    // Act_hi [8192][128] bf16 = 524288 floats
#define ACT_LO_OFF  (H_OFF + 524288)
#define BT_HI_OFF   (H_OFF + 1048576)        // BT_hi [2048][128] bf16 = 131072 floats
#define BT_LO_OFF   (H_OFF + 1179648)
#define ZCKO_OFF    (H_OFF + 1310720)        // ZcT_ko [10][4096] fp32
#define ZCWT_OFF    (H_OFF + 1351680)        // ZcT_wt [10][4096] fp32 (ends H_OFF+1392640)

// ---------------- pack: transpose + bf16 hi/lo split of [enc_w1|kap_w1] ----------------
__global__ __launch_bounds__(256) void pack_w_kernel(const float* __restrict__ enc_w1,
                                                     const float* __restrict__ kap_w1,
                                                     __bf16* __restrict__ WThi,
                                                     __bf16* __restrict__ WTlo)
{
    __shared__ float tile[64][65];
    int kt = blockIdx.x & 31;
    int ct = blockIdx.x >> 5;
    int k0 = kt * 64, c0 = ct * 64;
    int t = threadIdx.x;
    int lr = t >> 6, lc = t & 63;
#pragma unroll
    for (int i = 0; i < 16; ++i) {
        int k = k0 + lr + 4 * i;
        int c = c0 + lc;
        float v = 0.f;
        if (k < 2000) v = (c < 128) ? enc_w1[(size_t)k * 128 + c]
                                    : kap_w1[(size_t)k * 128 + (c - 128)];
        tile[lc][lr + 4 * i] = v;
    }
    __syncthreads();
#pragma unroll
    for (int i = 0; i < 16; ++i) {
        int c = c0 + lr + 4 * i;
        int k = k0 + lc;
        float v = tile[lr + 4 * i][lc];
        __bf16 h = (__bf16)v;
        __bf16 l = (__bf16)(v - (float)h);
        size_t idx = (size_t)c * 2048 + k;
        WThi[idx] = h;
        WTlo[idx] = l;
    }
}

// ---------------- pack: transpose + bf16 hi/lo split of dec_w2 [128][2000] -> BT [2048][128] ----
__global__ __launch_bounds__(256) void pack_dw2_kernel(const float* __restrict__ dw2,
                                                       __bf16* __restrict__ BThi,
                                                       __bf16* __restrict__ BTlo)
{
    __shared__ float tile[64][129];   // [jj][c]
    int j0 = blockIdx.x * 64;
    int t = threadIdx.x;
#pragma unroll
    for (int i = 0; i < 32; ++i) {
        int idx = i * 256 + t;
        int c = idx >> 6, jj = idx & 63;
        int j = j0 + jj;
        tile[jj][c] = (j < 2000) ? dw2[(size_t)c * 2000 + j] : 0.f;
    }
    __syncthreads();
#pragma unroll
    for (int i = 0; i < 32; ++i) {
        int idx = i * 256 + t;
        int jj = idx >> 7, c = idx & 127;
        float v = tile[jj][c];
        __bf16 h = (__bf16)v;
        size_t o = (size_t)(j0 + jj) * 128 + c;
        BThi[o] = h;
        BTlo[o] = (__bf16)(v - (float)h);
    }
}

// ---------------- class counts + prefix offsets ----------------
__global__ void counts_kernel(const int* __restrict__ wtl, const int* __restrict__ kol,
                              float* __restrict__ acc)
{
    __shared__ int cw[10], ck[10];
    int t = threadIdx.x;
    if (t < 10) { cw[t] = 0; ck[t] = 0; }
    __syncthreads();
    for (int i = t; i < 4096; i += 1024) {
        atomicAdd(&cw[wtl[i]], 1);
        atomicAdd(&ck[kol[i]], 1);
    }
    __syncthreads();
    if (t < 10) { acc[OFF_NWT + t] = (float)cw[t]; acc[OFF_NKO + t] = (float)ck[t]; }
    if (t == 0) {
        int* ai = (int*)acc;
        int aw = 0, ak = 0;
        for (int c = 0; c < 10; ++c) {
            ai[IOFF_WTOFF + c] = aw; aw += cw[c];
            ai[IOFF_KOOFF + c] = ak; ak += ck[c];
        }
        ai[IOFF_WTOFF + 10] = aw;
        ai[IOFF_KOOFF + 10] = ak;
    }
}

// ---------------- scatter Z into class-compacted TRANSPOSED arrays ----------------
// ZcT[d][slot]: coalesced columns for the contrast inner loop.
__global__ __launch_bounds__(256) void scatter_z_kernel(const float* __restrict__ Z,
                                                        const int* __restrict__ wtl,
                                                        const int* __restrict__ kol,
                                                        float* __restrict__ acc,
                                                        float* __restrict__ ZcWT,
                                                        float* __restrict__ ZcKO)
{
    int row = blockIdx.x * 256 + threadIdx.x;     // 0..8191
    int side = row >= 4096;                       // 0 = wt, 1 = ko
    int r = side ? row - 4096 : row;
    int c = side ? kol[r] : wtl[r];
    int* ai = (int*)acc;
    int off = side ? ai[IOFF_KOOFF + c] : ai[IOFF_WTOFF + c];
    int* ctr = ai + (side ? IOFF_KOCTR : IOFF_WTCTR) + c;
    int slot = off + atomicAdd(ctr, 1);
    float* dst = side ? ZcKO : ZcWT;
    const float* zr = Z + (size_t)row * 10;
#pragma unroll
    for (int d = 0; d < 10; ++d) dst[d * 4096 + slot] = zr[d];
}

// ---------------- GEMM1 (MFMA bf16x3): H[8192][256] = X[8192][2000] @ W[2000][256] ----------------
__global__ __launch_bounds__(512) void gemm1_kernel(const float* __restrict__ wt_x,
                                                    const float* __restrict__ ko_x,
                                                    const __bf16* __restrict__ WThi,
                                                    const __bf16* __restrict__ WTlo,
                                                    float* __restrict__ Hb)
{
    __shared__ short Bs[2][2][8192];   // [buf][hi/lo][unit*8 shorts] = 64 KB
    int t = threadIdx.x;
    int widx = t >> 6, lane = t & 63;
    int wm = widx >> 2, wn = widx & 3;
    int R0 = blockIdx.x * 32;
    const float* xb = (R0 < 4096) ? (wt_x + (size_t)R0 * 2000)
                                  : (ko_x + (size_t)(R0 - 4096) * 2000);
    int arow = wm * 16 + (lane & 15);
    const float* xrow = xb + (size_t)arow * 2000;
    int kboff = (lane >> 4) * 8;

    int cc0 = (t >> 2) & 15;
    int s0  = (t & 3) ^ ((cc0 >> 1) & 3);
    int col0 = (t >> 6) * 16 + cc0;
    size_t boff0 = (size_t)col0 * 2048 + s0 * 8;
    size_t boff1 = boff0 + (size_t)128 * 2048;

    f32x4 acc0, acc1, acc2, acc3;
#pragma unroll
    for (int r = 0; r < 4; ++r) { acc0[r] = 0.f; acc1[r] = 0.f; acc2[r] = 0.f; acc3[r] = 0.f; }

    uint4 bhA0, bhA1, blA0, blA1;
    uint4 bhB0, bhB1, blB0, blB1;
    float4 aA0, aA1, aB0, aB1;

#define GLOADB_(step, h0, h1, l0, l1) do { \
    h0 = *(const uint4*)(WThi + boff0 + (size_t)(step) * 32); \
    h1 = *(const uint4*)(WThi + boff1 + (size_t)(step) * 32); \
    l0 = *(const uint4*)(WTlo + boff0 + (size_t)(step) * 32); \
    l1 = *(const uint4*)(WTlo + boff1 + (size_t)(step) * 32); } while (0)

#define DSWRITE_(buf, h0, h1, l0, l1) do { \
    *(uint4*)&Bs[buf][0][t * 8]        = h0; \
    *(uint4*)&Bs[buf][0][4096 + t * 8] = h1; \
    *(uint4*)&Bs[buf][1][t * 8]        = l0; \
    *(uint4*)&Bs[buf][1][4096 + t * 8] = l1; } while (0)

#define GLOADA_(step, a0, a1) do { \
    int k0_ = (step) * 32; \
    int k_ = k0_ + kboff; \
    if (k0_ <= 1952) { \
        a0 = *(const float4*)(xrow + k_); \
        a1 = *(const float4*)(xrow + k_ + 4); \
    } else { \
        float t_[8]; \
        _Pragma("unroll") \
        for (int j = 0; j < 8; ++j) { int kk = k_ + j; t_[j] = (kk < 2000) ? xrow[kk] : 0.f; } \
        a0 = make_float4(t_[0], t_[1], t_[2], t_[3]); \
        a1 = make_float4(t_[4], t_[5], t_[6], t_[7]); } } while (0)

#define CONVA_(a0, a1, ahi, alo) do { \
    float av_[8] = {a0.x, a0.y, a0.z, a0.w, a1.x, a1.y, a1.z, a1.w}; \
    _Pragma("unroll") \
    for (int j = 0; j < 8; ++j) { \
        __bf16 h_ = (__bf16)av_[j]; \
        ahi[j] = h_; \
        alo[j] = (__bf16)(av_[j] - (float)h_); } } while (0)

#define MFMA_(buf) do { \
    _Pragma("unroll") \
    for (int nf = 0; nf < 4; ++nf) { \
        bf16x8 bhf = *(const bf16x8*)&Bs[buf][0][(ubase + nf * 64) * 8]; \
        bf16x8 blf = *(const bf16x8*)&Bs[buf][1][(ubase + nf * 64) * 8]; \
        f32x4* ac = (nf == 0) ? &acc0 : (nf == 1) ? &acc1 : (nf == 2) ? &acc2 : &acc3; \
        *ac = __builtin_amdgcn_mfma_f32_16x16x32_bf16(ahi, bhf, *ac, 0, 0, 0); \
        *ac = __builtin_amdgcn_mfma_f32_16x16x32_bf16(alo, bhf, *ac, 0, 0, 0); \
        *ac = __builtin_amdgcn_mfma_f32_16x16x32_bf16(ahi, blf, *ac, 0, 0, 0); } } while (0)

    GLOADB_(0, bhA0, bhA1, blA0, blA1); GLOADA_(0, aA0, aA1);
    GLOADB_(1, bhB0, bhB1, blB0, blB1); GLOADA_(1, aB0, aB1);
    DSWRITE_(0, bhA0, bhA1, blA0, blA1);
    __syncthreads();

    int cpr = lane & 15;
    int pph = (lane >> 4) ^ ((cpr >> 1) & 3);
    int ubase = (wn * 4) * 64 + cpr * 4 + pph;

    for (int it = 0; it < 32; ++it) {
        int st0 = it * 2;
        {
            bf16x8 ahi, alo;
            CONVA_(aA0, aA1, ahi, alo);
            if (st0 + 2 < 64) { GLOADB_(st0 + 2, bhA0, bhA1, blA0, blA1); GLOADA_(st0 + 2, aA0, aA1); }
            DSWRITE_(1, bhB0, bhB1, blB0, blB1);
            MFMA_(0);
            __syncthreads();
        }
        {
            bf16x8 ahi, alo;
            CONVA_(aB0, aB1, ahi, alo);
            if (st0 + 3 < 64) { GLOADB_(st0 + 3, bhB0, bhB1, blB0, blB1); GLOADA_(st0 + 3, aB0, aB1); }
            if (st0 + 2 < 64) DSWRITE_(0, bhA0, bhA1, blA0, blA1);
            MFMA_(1);
            __syncthreads();
        }
    }

#pragma unroll
    for (int r = 0; r < 4; ++r) {
        int row = R0 + wm * 16 + (lane >> 4) * 4 + r;
        size_t base = (size_t)row * 256 + wn * 64 + (lane & 15);
        Hb[base]      = acc0[r];
        Hb[base + 16] = acc1[r];
        Hb[base + 32] = acc2[r];
        Hb[base + 48] = acc3[r];
    }
#undef GLOADB_
#undef DSWRITE_
#undef GLOADA_
#undef CONVA_
#undef MFMA_
}

// ---------------- stage2: LN->ReLU->head matmuls per row ----------------
__global__ __launch_bounds__(128) void stage2_kernel(const float* __restrict__ Hb,
    const float* __restrict__ enc_b1, const float* __restrict__ enc_g, const float* __restrict__ enc_be,
    const float* __restrict__ enc_w2, const float* __restrict__ enc_b2,
    const float* __restrict__ kap_b1, const float* __restrict__ kap_g, const float* __restrict__ kap_be,
    const float* __restrict__ kap_w2, const float* __restrict__ kap_b2,
    float* __restrict__ Z, float* __restrict__ Kap)
{
    __shared__ float sh[128];
    int row  = blockIdx.x;
    int wave = threadIdx.x >> 6;
    int lane = threadIdx.x & 63;
    const float* hb = Hb + (size_t)row * 256 + wave * 128;
    const float* b1 = wave ? kap_b1 : enc_b1;
    const float* gg = wave ? kap_g  : enc_g;
    const float* bb = wave ? kap_be : enc_be;

    float h0 = hb[lane]      + b1[lane];
    float h1 = hb[lane + 64] + b1[lane + 64];
    float s = h0 + h1;
#pragma unroll
    for (int o = 32; o > 0; o >>= 1) s += __shfl_xor(s, o, 64);
    float m = s * (1.f / 128.f);
    float d0 = h0 - m, d1 = h1 - m;
    float v = d0 * d0 + d1 * d1;
#pragma unroll
    for (int o = 32; o > 0; o >>= 1) v += __shfl_xor(v, o, 64);
    v *= (1.f / 128.f);
    float sc = 1.f / sqrtf(v + 1e-5f);
    float r0 = fmaxf(fmaf(d0 * sc, gg[lane],      bb[lane]),      0.f);
    float r1 = fmaxf(fmaf(d1 * sc, gg[lane + 64], bb[lane + 64]), 0.f);

    if (wave == 0) { sh[lane] = r0; sh[lane + 64] = r1; }
    __syncthreads();

    if (wave == 0) {
        float mu = 0.f;
        if (lane < 10) {
            mu = enc_b2[lane];
            for (int c = 0; c < 128; ++c) mu = fmaf(sh[c], enc_w2[c * 10 + lane], mu);
        }
        float n2 = mu * mu;
#pragma unroll
        for (int o = 8; o > 0; o >>= 1) n2 += __shfl_xor(n2, o, 16);
        float inv = 1.f / fmaxf(sqrtf(n2), 1e-12f);
        if (lane < 10) Z[(size_t)row * 10 + lane] = mu * inv;
    } else {
        float p = r0 * kap_w2[lane] + r1 * kap_w2[lane + 64];
#pragma unroll
        for (int o = 32; o > 0; o >>= 1) p += __shfl_xor(p, o, 64);
        if (lane == 0) {
            float x = p + kap_b2[0];
            float sp = (x > 20.f) ? x : log1pf(expf(x));
            Kap[row] = sp + 1e-6f;
        }
    }
}

// ---------------- dec_act: a = ReLU(LN(z @ dw1 + db1)) -> bf16 hi/lo [8192][128] ----------------
__global__ __launch_bounds__(256) void dec_act_kernel(const float* __restrict__ Zb,
    const float* __restrict__ dw1, const float* __restrict__ db1,
    const float* __restrict__ dg,  const float* __restrict__ dbe,
    __bf16* __restrict__ Ahi, __bf16* __restrict__ Alo)
{
    int wave = threadIdx.x >> 6;
    int lane = threadIdx.x & 63;
    int row = blockIdx.x * 4 + wave;
    const float* zr = Zb + (size_t)row * 10;
    float z[10];
#pragma unroll
    for (int d = 0; d < 10; ++d) z[d] = zr[d];
    int c0 = lane, c1 = lane + 64;
    float h0 = db1[c0], h1 = db1[c1];
#pragma unroll
    for (int d = 0; d < 10; ++d) {
        h0 = fmaf(z[d], dw1[d * 128 + c0], h0);
        h1 = fmaf(z[d], dw1[d * 128 + c1], h1);
    }
    float s = h0 + h1;
#pragma unroll
    for (int o = 32; o > 0; o >>= 1) s += __shfl_xor(s, o, 64);
    float m = s * (1.f / 128.f);
    float d0 = h0 - m, d1 = h1 - m;
    float v = d0 * d0 + d1 * d1;
#pragma unroll
    for (int o = 32; o > 0; o >>= 1) v += __shfl_xor(v, o, 64);
    v *= (1.f / 128.f);
    float sc = 1.f / sqrtf(v + 1e-5f);
    float a0 = fmaxf(fmaf(d0 * sc, dg[c0], dbe[c0]), 0.f);
    float a1 = fmaxf(fmaf(d1 * sc, dg[c1], dbe[c1]), 0.f);
    __bf16 h0b = (__bf16)a0, h1b = (__bf16)a1;
    size_t base = (size_t)row * 128;
    Ahi[base + c0] = h0b;                 Ahi[base + c1] = h1b;
    Alo[base + c0] = (__bf16)(a0 - (float)h0b);
    Alo[base + c1] = (__bf16)(a1 - (float)h1b);
}

// ---------------- dec_gemm: rec = Act @ dw2 + b2, fused sq-err vs x (MFMA bf16x3) ----------------
__global__ __launch_bounds__(512) void dec_gemm_kernel(
    const __bf16* __restrict__ Ahi, const __bf16* __restrict__ Alo,
    const __bf16* __restrict__ BThi, const __bf16* __restrict__ BTlo,
    const float* __restrict__ wt_x, const float* __restrict__ ko_x,
    const float* __restrict__ db2, float* __restrict__ acc)
{
    __shared__ float rs[8];
    int t = threadIdx.x;
    int widx = t >> 6, lane = t & 63;
    int wm = widx >> 2, wn = widx & 3;
    int R0 = blockIdx.x * 32;
    const float* xbase = (R0 < 4096) ? wt_x : ko_x;
    int xr0 = ((R0 < 4096) ? R0 : R0 - 4096) + wm * 16 + (lane >> 4) * 4;

    size_t abase = (size_t)(R0 + wm * 16 + (lane & 15)) * 128 + (lane >> 4) * 8;
    bf16x8 ah0 = *(const bf16x8*)(Ahi + abase);
    bf16x8 ah1 = *(const bf16x8*)(Ahi + abase + 32);
    bf16x8 ah2 = *(const bf16x8*)(Ahi + abase + 64);
    bf16x8 ah3 = *(const bf16x8*)(Ahi + abase + 96);
    bf16x8 al0 = *(const bf16x8*)(Alo + abase);
    bf16x8 al1 = *(const bf16x8*)(Alo + abase + 32);
    bf16x8 al2 = *(const bf16x8*)(Alo + abase + 64);
    bf16x8 al3 = *(const bf16x8*)(Alo + abase + 96);

    float rsum = 0.f;
    for (int itn = 0; itn < 32; ++itn) {
        int col = itn * 64 + wn * 16 + (lane & 15);
        size_t bbase = (size_t)col * 128 + (lane >> 4) * 8;
        bf16x8 bh0 = *(const bf16x8*)(BThi + bbase);
        bf16x8 bh1 = *(const bf16x8*)(BThi + bbase + 32);
        bf16x8 bh2 = *(const bf16x8*)(BThi + bbase + 64);
        bf16x8 bh3 = *(const bf16x8*)(BThi + bbase + 96);
        bf16x8 bl0 = *(const bf16x8*)(BTlo + bbase);
        bf16x8 bl1 = *(const bf16x8*)(BTlo + bbase + 32);
        bf16x8 bl2 = *(const bf16x8*)(BTlo + bbase + 64);
        bf16x8 bl3 = *(const bf16x8*)(BTlo + bbase + 96);

        f32x4 a4;
#pragma unroll
        for (int r = 0; r < 4; ++r) a4[r] = 0.f;
        a4 = __builtin_amdgcn_mfma_f32_16x16x32_bf16(ah0, bh0, a4, 0, 0, 0);
        a4 = __builtin_amdgcn_mfma_f32_16x16x32_bf16(al0, bh0, a4, 0, 0, 0);
        a4 = __builtin_amdgcn_mfma_f32_16x16x32_bf16(ah0, bl0, a4, 0, 0, 0);
        a4 = __builtin_amdgcn_mfma_f32_16x16x32_bf16(ah1, bh1, a4, 0, 0, 0);
        a4 = __builtin_amdgcn_mfma_f32_16x16x32_bf16(al1, bh1, a4, 0, 0, 0);
        a4 = __builtin_amdgcn_mfma_f32_16x16x32_bf16(ah1, bl1, a4, 0, 0, 0);
        a4 = __builtin_amdgcn_mfma_f32_16x16x32_bf16(ah2, bh2, a4, 0, 0, 0);
        a4 = __builtin_amdgcn_mfma_f32_16x16x32_bf16(al2, bh2, a4, 0, 0, 0);
        a4 = __builtin_amdgcn_mfma_f32_16x16x32_bf16(ah2, bl2, a4, 0, 0, 0);
        a4 = __builtin_amdgcn_mfma_f32_16x16x32_bf16(ah3, bh3, a4, 0, 0, 0);
        a4 = __builtin_amdgcn_mfma_f32_16x16x32_bf16(al3, bh3, a4, 0, 0, 0);
        a4 = __builtin_amdgcn_mfma_f32_16x16x32_bf16(ah3, bl3, a4, 0, 0, 0);

        if (col < 2000) {
            float bb = db2[col];
#pragma unroll
            for (int r = 0; r < 4; ++r) {
                float xv = xbase[(size_t)(xr0 + r) * 2000 + col];
                float e = a4[r] + bb - xv;
                rsum = fmaf(e, e, rsum);
            }
        }
    }
#pragma unroll
    for (int o = 32; o > 0; o >>= 1) rsum += __shfl_xor(rsum, o, 64);
    if (lane == 0) rs[widx] = rsum;
    __syncthreads();
    if (t == 0) {
        float s = 0.f;
#pragma unroll
        for (int w = 0; w < 8; ++w) s += rs[w];
        atomicAdd(&acc[OFF_REC], s);
    }
}

// ---------------- fused contrastive pass over class-compacted columns ----------------
// One wave per A-row (8192 rows, both directions). Inner loop: coalesced, branch-free.
__global__ __launch_bounds__(256) void contrast_kernel(const float* __restrict__ Z,
                                                       const int* __restrict__ wtl,
                                                       const int* __restrict__ kol,
                                                       const float* __restrict__ ZcWT,
                                                       const float* __restrict__ ZcKO,
                                                       float* __restrict__ acc)
{
    int i    = blockIdx.x * 4 + (threadIdx.x >> 6);   // 0..8191
    int lane = threadIdx.x & 63;
    int side = i >= 4096;                             // 0: wt row vs ko cols; 1: ko row vs wt cols
    int r = side ? i - 4096 : i;
    int ci = side ? kol[r] : wtl[r];
    const int* ai = (const int*)acc;
    int start = side ? ai[IOFF_WTOFF + ci] : ai[IOFF_KOOFF + ci];
    int end   = side ? ai[IOFF_WTOFF + ci + 1] : ai[IOFF_KOOFF + ci + 1];
    int n = end - start;
    if (n <= 0) return;                               // other side empty -> class invalid
    const float* ZcT = side ? ZcWT : ZcKO;
    float za[10];
#pragma unroll
    for (int d = 0; d < 10; ++d) za[d] = Z[(size_t)i * 10 + d];
    float se = 0.f, ss = 0.f;
    for (int j = start + lane; j < end; j += 64) {
        float s = 0.f;
#pragma unroll
        for (int d = 0; d < 10; ++d) s = fmaf(za[d], ZcT[d * 4096 + j], s);
        s *= 10.f;                        // 1/TAU
        se += expf(s - 10.f);             // |S| <= 10
        ss += s;
    }
#pragma unroll
    for (int o = 32; o > 0; o >>= 1) { se += __shfl_xor(se, o, 64); ss += __shfl_xor(ss, o, 64); }
    if (lane == 0) {
        float lse = 10.f + logf(se);
        atomicAdd(&acc[(side ? OFF_L2 : OFF_L1) + ci], lse - ss / (float)n);
    }
}

// ---------------- alignment stats + kappa reduction ----------------
__global__ __launch_bounds__(256) void align_kernel(const float* __restrict__ Z,
                                                    const int* __restrict__ wtl,
                                                    const int* __restrict__ kol,
                                                    const float* __restrict__ Kap,
                                                    float* __restrict__ acc)
{
    __shared__ float cL[10], qL[10], sL[100], ks;
    int t = threadIdx.x;
    if (t < 10) { cL[t] = 0.f; qL[t] = 0.f; }
    if (t < 100) sL[t] = 0.f;
    if (t == 0) ks = 0.f;
    __syncthreads();
    int row = blockIdx.x * 256 + t;
    int c = (row < 4096) ? wtl[row] : kol[row - 4096];
    float zz[10]; float q = 0.f;
#pragma unroll
    for (int d = 0; d < 10; ++d) { zz[d] = Z[(size_t)row * 10 + d]; q = fmaf(zz[d], zz[d], q); }
    atomicAdd(&cL[c], 1.f);
    atomicAdd(&qL[c], q);
#pragma unroll
    for (int d = 0; d < 10; ++d) atomicAdd(&sL[c * 10 + d], zz[d]);
    atomicAdd(&ks, Kap[row]);
    __syncthreads();
    if (t < 10)  { atomicAdd(&acc[OFF_CNT + t], cL[t]); atomicAdd(&acc[OFF_ZSQ + t], qL[t]); }
    if (t < 100) atomicAdd(&acc[OFF_ZSUM + t], sL[t]);
    if (t == 0)  atomicAdd(&acc[OFF_KSUM + (blockIdx.x >= 16)], ks);
}

// ---------------- finalize ----------------
__global__ void finalize_kernel(const float* __restrict__ acc, float* __restrict__ out)
{
    float total = 0.f, nsh = 0.f;
    for (int c = 0; c < 10; ++c) {
        float nw = acc[OFF_NWT + c], nk = acc[OFF_NKO + c];
        if (nw > 0.5f && nk > 0.5f) {
            float l1 = acc[OFF_L1 + c] / nw;
            float l2 = acc[OFF_L2 + c] / nk;
            total += 0.5f * (l1 + l2);
            nsh += 1.f;
        }
    }
    float contrast = (nsh > 0.f) ? total / nsh : 0.f;
    float ap = 0.f, np_ = 0.f;
    for (int c = 0; c < 10; ++c) {
        float cn = acc[OFF_CNT + c];
        if (cn > 0.5f) {
            float mu2 = 0.f;
            for (int d = 0; d < 10; ++d) {
                float mm = acc[OFF_ZSUM + c * 10 + d] / cn;
                mu2 = fmaf(mm, mm, mu2);
            }
            ap += acc[OFF_ZSQ + c] / cn - mu2;
            np_ += 1.f;
        }
    }
    float align = (np_ > 0.f) ? ap / np_ : 0.f;
    float kl = 0.01f * (acc[OFF_KSUM + 0] + acc[OFF_KSUM + 1]) * (1.f / 4096.f);
    float recon = acc[OFF_REC] * (1.f / 8192000.f);
    out[0] = recon + kl + 1.0f * contrast + 0.5f * align;
}

extern "C" void kernel_launch(void* const* d_in, const int* in_sizes, int n_in,
                              void* d_out, int out_size, void* d_ws, size_t ws_size,
                              hipStream_t stream)
{
    const float* wt_x   = (const float*)d_in[0];
    const float* ko_x   = (const float*)d_in[1];
    const int*   wtl    = (const int*)d_in[2];
    const int*   kol    = (const int*)d_in[3];
    const float* enc_w1 = (const float*)d_in[4];
    const float* enc_b1 = (const float*)d_in[5];
    const float* enc_g  = (const float*)d_in[6];
    const float* enc_be = (const float*)d_in[7];
    const float* enc_w2 = (const float*)d_in[8];
    const float* enc_b2 = (const float*)d_in[9];
    const float* kap_w1 = (const float*)d_in[10];
    const float* kap_b1 = (const float*)d_in[11];
    const float* kap_g  = (const float*)d_in[12];
    const float* kap_be = (const float*)d_in[13];
    const float* kap_w2 = (const float*)d_in[14];
    const float* kap_b2 = (const float*)d_in[15];
    const float* dw1    = (const float*)d_in[16];
    const float* db1    = (const float*)d_in[17];
    const float* dg     = (const float*)d_in[18];
    const float* dbe    = (const float*)d_in[19];
    const float* dw2    = (const float*)d_in[20];
    const float* db2    = (const float*)d_in[21];

    float* ws  = (float*)d_ws;
    float* acc = ws;
    __bf16* WThi = (__bf16*)(ws + WT_OFF);
    __bf16* WTlo = (__bf16*)(ws + WTLO_OFF);
    float* Hb  = ws + H_OFF;
    float* Zb  = ws + Z_OFF;
    float* Kap = ws + KAP_OFF;
    __bf16* Ahi  = (__bf16*)(ws + ACT_HI_OFF);
    __bf16* Alo  = (__bf16*)(ws + ACT_LO_OFF);
    __bf16* BThi = (__bf16*)(ws + BT_HI_OFF);
    __bf16* BTlo = (__bf16*)(ws + BT_LO_OFF);
    float* ZcKO = ws + ZCKO_OFF;
    float* ZcWT = ws + ZCWT_OFF;

    hipMemsetAsync(acc, 0, ACC_FLOATS * sizeof(float), stream);
    pack_w_kernel<<<128, 256, 0, stream>>>(enc_w1, kap_w1, WThi, WTlo);
    counts_kernel<<<1, 1024, 0, stream>>>(wtl, kol, acc);
    gemm1_kernel<<<256, 512, 0, stream>>>(wt_x, ko_x, WThi, WTlo, Hb);
    stage2_kernel<<<8192, 128, 0, stream>>>(Hb, enc_b1, enc_g, enc_be, enc_w2, enc_b2,
                                            kap_b1, kap_g, kap_be, kap_w2, kap_b2, Zb, Kap);
    // H is dead from here; Act/BT/ZcT overlay it
    pack_dw2_kernel<<<32, 256, 0, stream>>>(dw2, BThi, BTlo);
    dec_act_kernel<<<2048, 256, 0, stream>>>(Zb, dw1, db1, dg, dbe, Ahi, Alo);
    scatter_z_kernel<<<32, 256, 0, stream>>>(Zb, wtl, kol, acc, ZcWT, ZcKO);
    contrast_kernel<<<2048, 256, 0, stream>>>(Zb, wtl, kol, ZcWT, ZcKO, acc);
    align_kernel<<<32, 256, 0, stream>>>(Zb, wtl, kol, Kap, acc);
    dec_gemm_kernel<<<256, 512, 0, stream>>>(Ahi, Alo, BThi, BTlo, wt_x, ko_x, db2, acc);
    finalize_kernel<<<1, 1, 0, stream>>>(acc, (float*)d_out);
}

// Round 6
// 282.115 us; speedup vs baseline: 2.2360x; 1.0837x over previous
//
#include <hip/hip_runtime.h>
#include <math.h>

typedef __attribute__((ext_vector_type(8))) __bf16 bf16x8;
typedef __attribute__((ext_vector_type(4))) float f32x4;

// ---- workspace layout (float offsets) ----
#define OFF_NWT   0
#define OFF_NKO   10
#define OFF_L1    20
#define OFF_L2    30
#define OFF_CNT   40
#define OFF_ZSUM  50
#define OFF_ZSQ   150
#define OFF_KSUM  160
#define OFF_REC   162
// int-typed slots (indices into the same float array, viewed as int*)
#define IOFF_WTOFF 192      // int wtOff[11]
#define IOFF_KOOFF 204      // int koOff[11]
#define IOFF_WTCTR 216      // int wtCtr[10]  (KOCTR = WTCTR+10, consecutive)
#define IOFF_KOCTR 226      // int koCtr[10]
#define ACC_FLOATS 256

#define WT_OFF    256                        // WThi [256][2048] bf16 = 262144 floats
#define WTLO_OFF  (WT_OFF + 262144)          // WTlo
#define H_OFF     (WTLO_OFF + 262144)        // H [8192][256] fp32 -- dead after stage2
#define Z_OFF     (H_OFF + 8192*256)         // Z [8192][10]
#define KAP_OFF   (Z_OFF + 8192*10)          // kappa [8192]

// overlays on the dead H region (written only after stage2 consumed H):
#define ACT_HI_OFF  H_OFF                    // Act_hi [8192][128] bf16 = 524288 floats
#define ACT_LO_OFF  (H_OFF + 524288)
#define BT_HI_OFF   (H_OFF + 1048576)        // BT_hi [2048][128] bf16 = 131072 floats
#define BT_LO_OFF   (H_OFF + 1179648)
#define ZCKO_OFF    (H_OFF + 1310720)        // ZcT_ko [10][4096] fp32
#define ZCWT_OFF    (H_OFF + 1351680)        // ZcT_wt [10][4096] fp32
#define PART_OFF    (H_OFF + 1392640)        // align partials [32][128] fp32 (ends < H_OFF+2097152)

// ---------------- pack: transpose + bf16 hi/lo split of [enc_w1|kap_w1] ----------------
__global__ __launch_bounds__(256) void pack_w_kernel(const float* __restrict__ enc_w1,
                                                     const float* __restrict__ kap_w1,
                                                     __bf16* __restrict__ WThi,
                                                     __bf16* __restrict__ WTlo)
{
    __shared__ float tile[64][65];
    int kt = blockIdx.x & 31;
    int ct = blockIdx.x >> 5;
    int k0 = kt * 64, c0 = ct * 64;
    int t = threadIdx.x;
    int lr = t >> 6, lc = t & 63;
#pragma unroll
    for (int i = 0; i < 16; ++i) {
        int k = k0 + lr + 4 * i;
        int c = c0 + lc;
        float v = 0.f;
        if (k < 2000) v = (c < 128) ? enc_w1[(size_t)k * 128 + c]
                                    : kap_w1[(size_t)k * 128 + (c - 128)];
        tile[lc][lr + 4 * i] = v;
    }
    __syncthreads();
#pragma unroll
    for (int i = 0; i < 16; ++i) {
        int c = c0 + lr + 4 * i;
        int k = k0 + lc;
        float v = tile[lr + 4 * i][lc];
        __bf16 h = (__bf16)v;
        __bf16 l = (__bf16)(v - (float)h);
        size_t idx = (size_t)c * 2048 + k;
        WThi[idx] = h;
        WTlo[idx] = l;
    }
}

// ---------------- pack: transpose + bf16 hi/lo split of dec_w2 [128][2000] -> BT [2048][128] ----
__global__ __launch_bounds__(256) void pack_dw2_kernel(const float* __restrict__ dw2,
                                                       __bf16* __restrict__ BThi,
                                                       __bf16* __restrict__ BTlo)
{
    __shared__ float tile[64][129];   // [jj][c]
    int j0 = blockIdx.x * 64;
    int t = threadIdx.x;
#pragma unroll
    for (int i = 0; i < 32; ++i) {
        int idx = i * 256 + t;
        int c = idx >> 6, jj = idx & 63;
        int j = j0 + jj;
        tile[jj][c] = (j < 2000) ? dw2[(size_t)c * 2000 + j] : 0.f;
    }
    __syncthreads();
#pragma unroll
    for (int i = 0; i < 32; ++i) {
        int idx = i * 256 + t;
        int jj = idx >> 7, c = idx & 127;
        float v = tile[jj][c];
        __bf16 h = (__bf16)v;
        size_t o = (size_t)(j0 + jj) * 128 + c;
        BThi[o] = h;
        BTlo[o] = (__bf16)(v - (float)h);
    }
}

// ---------------- class counts + prefix offsets ----------------
__global__ void counts_kernel(const int* __restrict__ wtl, const int* __restrict__ kol,
                              float* __restrict__ acc)
{
    __shared__ int cw[10], ck[10];
    int t = threadIdx.x;
    if (t < 10) { cw[t] = 0; ck[t] = 0; }
    __syncthreads();
    for (int i = t; i < 4096; i += 1024) {
        atomicAdd(&cw[wtl[i]], 1);
        atomicAdd(&ck[kol[i]], 1);
    }
    __syncthreads();
    if (t < 10) { acc[OFF_NWT + t] = (float)cw[t]; acc[OFF_NKO + t] = (float)ck[t]; }
    if (t == 0) {
        int* ai = (int*)acc;
        int aw = 0, ak = 0;
        for (int c = 0; c < 10; ++c) {
            ai[IOFF_WTOFF + c] = aw; aw += cw[c];
            ai[IOFF_KOOFF + c] = ak; ak += ck[c];
        }
        ai[IOFF_WTOFF + 10] = aw;
        ai[IOFF_KOOFF + 10] = ak;
    }
}

// ---------------- scatter Z into class-compacted TRANSPOSED arrays ----------------
// Block-level LDS ranking; only 20 global fetch-adds per block (vs 1 per row).
__global__ __launch_bounds__(256) void scatter_z_kernel(const float* __restrict__ Z,
                                                        const int* __restrict__ wtl,
                                                        const int* __restrict__ kol,
                                                        float* __restrict__ acc,
                                                        float* __restrict__ ZcWT,
                                                        float* __restrict__ ZcKO)
{
    __shared__ int lcnt[20];
    __shared__ int lbase[20];
    int t = threadIdx.x;
    if (t < 20) lcnt[t] = 0;
    __syncthreads();
    int row = blockIdx.x * 256 + t;               // 0..8191
    int side = row >= 4096;                       // 0 = wt, 1 = ko
    int r = side ? row - 4096 : row;
    int c = side ? kol[r] : wtl[r];
    int key = side * 10 + c;
    int myrank = atomicAdd(&lcnt[key], 1);
    __syncthreads();
    int* ai = (int*)acc;
    if (t < 20 && lcnt[t] > 0)
        lbase[t] = atomicAdd(&ai[IOFF_WTCTR + t], lcnt[t]);   // WTCTR..KOCTR consecutive
    __syncthreads();
    int off = side ? ai[IOFF_KOOFF + c] : ai[IOFF_WTOFF + c];
    int slot = off + lbase[key] + myrank;
    float* dst = side ? ZcKO : ZcWT;
    const float* zr = Z + (size_t)row * 10;
#pragma unroll
    for (int d = 0; d < 10; ++d) dst[d * 4096 + slot] = zr[d];
}

// ---------------- GEMM1 (MFMA bf16x3): H[8192][256] = X[8192][2000] @ W[2000][256] ----------------
__global__ __launch_bounds__(512) void gemm1_kernel(const float* __restrict__ wt_x,
                                                    const float* __restrict__ ko_x,
                                                    const __bf16* __restrict__ WThi,
                                                    const __bf16* __restrict__ WTlo,
                                                    float* __restrict__ Hb)
{
    __shared__ short Bs[2][2][8192];   // [buf][hi/lo][unit*8 shorts] = 64 KB
    int t = threadIdx.x;
    int widx = t >> 6, lane = t & 63;
    int wm = widx >> 2, wn = widx & 3;
    int R0 = blockIdx.x * 32;
    const float* xb = (R0 < 4096) ? (wt_x + (size_t)R0 * 2000)
                                  : (ko_x + (size_t)(R0 - 4096) * 2000);
    int arow = wm * 16 + (lane & 15);
    const float* xrow = xb + (size_t)arow * 2000;
    int kboff = (lane >> 4) * 8;

    int cc0 = (t >> 2) & 15;
    int s0  = (t & 3) ^ ((cc0 >> 1) & 3);
    int col0 = (t >> 6) * 16 + cc0;
    size_t boff0 = (size_t)col0 * 2048 + s0 * 8;
    size_t boff1 = boff0 + (size_t)128 * 2048;

    f32x4 acc0, acc1, acc2, acc3;
#pragma unroll
    for (int r = 0; r < 4; ++r) { acc0[r] = 0.f; acc1[r] = 0.f; acc2[r] = 0.f; acc3[r] = 0.f; }

    uint4 bhA0, bhA1, blA0, blA1;
    uint4 bhB0, bhB1, blB0, blB1;
    float4 aA0, aA1, aB0, aB1;

#define GLOADB_(step, h0, h1, l0, l1) do { \
    h0 = *(const uint4*)(WThi + boff0 + (size_t)(step) * 32); \
    h1 = *(const uint4*)(WThi + boff1 + (size_t)(step) * 32); \
    l0 = *(const uint4*)(WTlo + boff0 + (size_t)(step) * 32); \
    l1 = *(const uint4*)(WTlo + boff1 + (size_t)(step) * 32); } while (0)

#define DSWRITE_(buf, h0, h1, l0, l1) do { \
    *(uint4*)&Bs[buf][0][t * 8]        = h0; \
    *(uint4*)&Bs[buf][0][4096 + t * 8] = h1; \
    *(uint4*)&Bs[buf][1][t * 8]        = l0; \
    *(uint4*)&Bs[buf][1][4096 + t * 8] = l1; } while (0)

#define GLOADA_(step, a0, a1) do { \
    int k0_ = (step) * 32; \
    int k_ = k0_ + kboff; \
    if (k0_ <= 1952) { \
        a0 = *(const float4*)(xrow + k_); \
        a1 = *(const float4*)(xrow + k_ + 4); \
    } else { \
        float t_[8]; \
        _Pragma("unroll") \
        for (int j = 0; j < 8; ++j) { int kk = k_ + j; t_[j] = (kk < 2000) ? xrow[kk] : 0.f; } \
        a0 = make_float4(t_[0], t_[1], t_[2], t_[3]); \
        a1 = make_float4(t_[4], t_[5], t_[6], t_[7]); } } while (0)

#define CONVA_(a0, a1, ahi, alo) do { \
    float av_[8] = {a0.x, a0.y, a0.z, a0.w, a1.x, a1.y, a1.z, a1.w}; \
    _Pragma("unroll") \
    for (int j = 0; j < 8; ++j) { \
        __bf16 h_ = (__bf16)av_[j]; \
        ahi[j] = h_; \
        alo[j] = (__bf16)(av_[j] - (float)h_); } } while (0)

#define MFMA_(buf) do { \
    _Pragma("unroll") \
    for (int nf = 0; nf < 4; ++nf) { \
        bf16x8 bhf = *(const bf16x8*)&Bs[buf][0][(ubase + nf * 64) * 8]; \
        bf16x8 blf = *(const bf16x8*)&Bs[buf][1][(ubase + nf * 64) * 8]; \
        f32x4* ac = (nf == 0) ? &acc0 : (nf == 1) ? &acc1 : (nf == 2) ? &acc2 : &acc3; \
        *ac = __builtin_amdgcn_mfma_f32_16x16x32_bf16(ahi, bhf, *ac, 0, 0, 0); \
        *ac = __builtin_amdgcn_mfma_f32_16x16x32_bf16(alo, bhf, *ac, 0, 0, 0); \
        *ac = __builtin_amdgcn_mfma_f32_16x16x32_bf16(ahi, blf, *ac, 0, 0, 0); } } while (0)

    GLOADB_(0, bhA0, bhA1, blA0, blA1); GLOADA_(0, aA0, aA1);
    GLOADB_(1, bhB0, bhB1, blB0, blB1); GLOADA_(1, aB0, aB1);
    DSWRITE_(0, bhA0, bhA1, blA0, blA1);
    __syncthreads();

    int cpr = lane & 15;
    int pph = (lane >> 4) ^ ((cpr >> 1) & 3);
    int ubase = (wn * 4) * 64 + cpr * 4 + pph;

    for (int it = 0; it < 32; ++it) {
        int st0 = it * 2;
        {
            bf16x8 ahi, alo;
            CONVA_(aA0, aA1, ahi, alo);
            if (st0 + 2 < 64) { GLOADB_(st0 + 2, bhA0, bhA1, blA0, blA1); GLOADA_(st0 + 2, aA0, aA1); }
            DSWRITE_(1, bhB0, bhB1, blB0, blB1);
            MFMA_(0);
            __syncthreads();
        }
        {
            bf16x8 ahi, alo;
            CONVA_(aB0, aB1, ahi, alo);
            if (st0 + 3 < 64) { GLOADB_(st0 + 3, bhB0, bhB1, blB0, blB1); GLOADA_(st0 + 3, aB0, aB1); }
            if (st0 + 2 < 64) DSWRITE_(0, bhA0, bhA1, blA0, blA1);
            MFMA_(1);
            __syncthreads();
        }
    }

#pragma unroll
    for (int r = 0; r < 4; ++r) {
        int row = R0 + wm * 16 + (lane >> 4) * 4 + r;
        size_t base = (size_t)row * 256 + wn * 64 + (lane & 15);
        Hb[base]      = acc0[r];
        Hb[base + 16] = acc1[r];
        Hb[base + 32] = acc2[r];
        Hb[base + 48] = acc3[r];
    }
#undef GLOADB_
#undef DSWRITE_
#undef GLOADA_
#undef CONVA_
#undef MFMA_
}

// ---------------- stage2: LN->ReLU->head matmuls per row ----------------
__global__ __launch_bounds__(128) void stage2_kernel(const float* __restrict__ Hb,
    const float* __restrict__ enc_b1, const float* __restrict__ enc_g, const float* __restrict__ enc_be,
    const float* __restrict__ enc_w2, const float* __restrict__ enc_b2,
    const float* __restrict__ kap_b1, const float* __restrict__ kap_g, const float* __restrict__ kap_be,
    const float* __restrict__ kap_w2, const float* __restrict__ kap_b2,
    float* __restrict__ Z, float* __restrict__ Kap)
{
    __shared__ float sh[128];
    int row  = blockIdx.x;
    int wave = threadIdx.x >> 6;
    int lane = threadIdx.x & 63;
    const float* hb = Hb + (size_t)row * 256 + wave * 128;
    const float* b1 = wave ? kap_b1 : enc_b1;
    const float* gg = wave ? kap_g  : enc_g;
    const float* bb = wave ? kap_be : enc_be;

    float h0 = hb[lane]      + b1[lane];
    float h1 = hb[lane + 64] + b1[lane + 64];
    float s = h0 + h1;
#pragma unroll
    for (int o = 32; o > 0; o >>= 1) s += __shfl_xor(s, o, 64);
    float m = s * (1.f / 128.f);
    float d0 = h0 - m, d1 = h1 - m;
    float v = d0 * d0 + d1 * d1;
#pragma unroll
    for (int o = 32; o > 0; o >>= 1) v += __shfl_xor(v, o, 64);
    v *= (1.f / 128.f);
    float sc = 1.f / sqrtf(v + 1e-5f);
    float r0 = fmaxf(fmaf(d0 * sc, gg[lane],      bb[lane]),      0.f);
    float r1 = fmaxf(fmaf(d1 * sc, gg[lane + 64], bb[lane + 64]), 0.f);

    if (wave == 0) { sh[lane] = r0; sh[lane + 64] = r1; }
    __syncthreads();

    if (wave == 0) {
        float mu = 0.f;
        if (lane < 10) {
            mu = enc_b2[lane];
            for (int c = 0; c < 128; ++c) mu = fmaf(sh[c], enc_w2[c * 10 + lane], mu);
        }
        float n2 = mu * mu;
#pragma unroll
        for (int o = 8; o > 0; o >>= 1) n2 += __shfl_xor(n2, o, 16);
        float inv = 1.f / fmaxf(sqrtf(n2), 1e-12f);
        if (lane < 10) Z[(size_t)row * 10 + lane] = mu * inv;
    } else {
        float p = r0 * kap_w2[lane] + r1 * kap_w2[lane + 64];
#pragma unroll
        for (int o = 32; o > 0; o >>= 1) p += __shfl_xor(p, o, 64);
        if (lane == 0) {
            float x = p + kap_b2[0];
            float sp = (x > 20.f) ? x : log1pf(expf(x));
            Kap[row] = sp + 1e-6f;
        }
    }
}

// ---------------- dec_act: a = ReLU(LN(z @ dw1 + db1)) -> bf16 hi/lo [8192][128] ----------------
__global__ __launch_bounds__(256) void dec_act_kernel(const float* __restrict__ Zb,
    const float* __restrict__ dw1, const float* __restrict__ db1,
    const float* __restrict__ dg,  const float* __restrict__ dbe,
    __bf16* __restrict__ Ahi, __bf16* __restrict__ Alo)
{
    int wave = threadIdx.x >> 6;
    int lane = threadIdx.x & 63;
    int row = blockIdx.x * 4 + wave;
    const float* zr = Zb + (size_t)row * 10;
    float z[10];
#pragma unroll
    for (int d = 0; d < 10; ++d) z[d] = zr[d];
    int c0 = lane, c1 = lane + 64;
    float h0 = db1[c0], h1 = db1[c1];
#pragma unroll
    for (int d = 0; d < 10; ++d) {
        h0 = fmaf(z[d], dw1[d * 128 + c0], h0);
        h1 = fmaf(z[d], dw1[d * 128 + c1], h1);
    }
    float s = h0 + h1;
#pragma unroll
    for (int o = 32; o > 0; o >>= 1) s += __shfl_xor(s, o, 64);
    float m = s * (1.f / 128.f);
    float d0 = h0 - m, d1 = h1 - m;
    float v = d0 * d0 + d1 * d1;
#pragma unroll
    for (int o = 32; o > 0; o >>= 1) v += __shfl_xor(v, o, 64);
    v *= (1.f / 128.f);
    float sc = 1.f / sqrtf(v + 1e-5f);
    float a0 = fmaxf(fmaf(d0 * sc, dg[c0], dbe[c0]), 0.f);
    float a1 = fmaxf(fmaf(d1 * sc, dg[c1], dbe[c1]), 0.f);
    __bf16 h0b = (__bf16)a0, h1b = (__bf16)a1;
    size_t base = (size_t)row * 128;
    Ahi[base + c0] = h0b;                 Ahi[base + c1] = h1b;
    Alo[base + c0] = (__bf16)(a0 - (float)h0b);
    Alo[base + c1] = (__bf16)(a1 - (float)h1b);
}

// ---------------- dec_gemm: rec = Act @ dw2 + b2, fused sq-err vs x (MFMA bf16x3) ----------------
__global__ __launch_bounds__(512) void dec_gemm_kernel(
    const __bf16* __restrict__ Ahi, const __bf16* __restrict__ Alo,
    const __bf16* __restrict__ BThi, const __bf16* __restrict__ BTlo,
    const float* __restrict__ wt_x, const float* __restrict__ ko_x,
    const float* __restrict__ db2, float* __restrict__ acc)
{
    __shared__ float rs[8];
    int t = threadIdx.x;
    int widx = t >> 6, lane = t & 63;
    int wm = widx >> 2, wn = widx & 3;
    int R0 = blockIdx.x * 32;
    const float* xbase = (R0 < 4096) ? wt_x : ko_x;
    int xr0 = ((R0 < 4096) ? R0 : R0 - 4096) + wm * 16 + (lane >> 4) * 4;

    size_t abase = (size_t)(R0 + wm * 16 + (lane & 15)) * 128 + (lane >> 4) * 8;
    bf16x8 ah0 = *(const bf16x8*)(Ahi + abase);
    bf16x8 ah1 = *(const bf16x8*)(Ahi + abase + 32);
    bf16x8 ah2 = *(const bf16x8*)(Ahi + abase + 64);
    bf16x8 ah3 = *(const bf16x8*)(Ahi + abase + 96);
    bf16x8 al0 = *(const bf16x8*)(Alo + abase);
    bf16x8 al1 = *(const bf16x8*)(Alo + abase + 32);
    bf16x8 al2 = *(const bf16x8*)(Alo + abase + 64);
    bf16x8 al3 = *(const bf16x8*)(Alo + abase + 96);

    float rsum = 0.f;
    for (int itn = 0; itn < 32; ++itn) {
        int col = itn * 64 + wn * 16 + (lane & 15);
        size_t bbase = (size_t)col * 128 + (lane >> 4) * 8;
        bf16x8 bh0 = *(const bf16x8*)(BThi + bbase);
        bf16x8 bh1 = *(const bf16x8*)(BThi + bbase + 32);
        bf16x8 bh2 = *(const bf16x8*)(BThi + bbase + 64);
        bf16x8 bh3 = *(const bf16x8*)(BThi + bbase + 96);
        bf16x8 bl0 = *(const bf16x8*)(BTlo + bbase);
        bf16x8 bl1 = *(const bf16x8*)(BTlo + bbase + 32);
        bf16x8 bl2 = *(const bf16x8*)(BTlo + bbase + 64);
        bf16x8 bl3 = *(const bf16x8*)(BTlo + bbase + 96);

        f32x4 a4;
#pragma unroll
        for (int r = 0; r < 4; ++r) a4[r] = 0.f;
        a4 = __builtin_amdgcn_mfma_f32_16x16x32_bf16(ah0, bh0, a4, 0, 0, 0);
        a4 = __builtin_amdgcn_mfma_f32_16x16x32_bf16(al0, bh0, a4, 0, 0, 0);
        a4 = __builtin_amdgcn_mfma_f32_16x16x32_bf16(ah0, bl0, a4, 0, 0, 0);
        a4 = __builtin_amdgcn_mfma_f32_16x16x32_bf16(ah1, bh1, a4, 0, 0, 0);
        a4 = __builtin_amdgcn_mfma_f32_16x16x32_bf16(al1, bh1, a4, 0, 0, 0);
        a4 = __builtin_amdgcn_mfma_f32_16x16x32_bf16(ah1, bl1, a4, 0, 0, 0);
        a4 = __builtin_amdgcn_mfma_f32_16x16x32_bf16(ah2, bh2, a4, 0, 0, 0);
        a4 = __builtin_amdgcn_mfma_f32_16x16x32_bf16(al2, bh2, a4, 0, 0, 0);
        a4 = __builtin_amdgcn_mfma_f32_16x16x32_bf16(ah2, bl2, a4, 0, 0, 0);
        a4 = __builtin_amdgcn_mfma_f32_16x16x32_bf16(ah3, bh3, a4, 0, 0, 0);
        a4 = __builtin_amdgcn_mfma_f32_16x16x32_bf16(al3, bh3, a4, 0, 0, 0);
        a4 = __builtin_amdgcn_mfma_f32_16x16x32_bf16(ah3, bl3, a4, 0, 0, 0);

        if (col < 2000) {
            float bb = db2[col];
#pragma unroll
            for (int r = 0; r < 4; ++r) {
                float xv = xbase[(size_t)(xr0 + r) * 2000 + col];
                float e = a4[r] + bb - xv;
                rsum = fmaf(e, e, rsum);
            }
        }
    }
#pragma unroll
    for (int o = 32; o > 0; o >>= 1) rsum += __shfl_xor(rsum, o, 64);
    if (lane == 0) rs[widx] = rsum;
    __syncthreads();
    if (t == 0) {
        float s = 0.f;
#pragma unroll
        for (int w = 0; w < 8; ++w) s += rs[w];
        atomicAdd(&acc[OFF_REC], s);
    }
}

// ---------------- contrast v3: one block per (class, side); zero global atomics ----------------
// Block b: c=b>>1, side=b&1. A-rows and B-cols both from compacted ZcT arrays.
// 16 waves sweep A-rows; per-wave register accumulation; one plain store per block.
__global__ __launch_bounds__(1024) void contrast_kernel(const float* __restrict__ ZcWT,
                                                        const float* __restrict__ ZcKO,
                                                        float* __restrict__ acc)
{
    __shared__ float wsums[16];
    int b = blockIdx.x;
    int c = b >> 1, side = b & 1;
    const int* ai = (const int*)acc;
    int aStart = side ? ai[IOFF_KOOFF + c]     : ai[IOFF_WTOFF + c];
    int aEnd   = side ? ai[IOFF_KOOFF + c + 1] : ai[IOFF_WTOFF + c + 1];
    int bStart = side ? ai[IOFF_WTOFF + c]     : ai[IOFF_KOOFF + c];
    int bEnd   = side ? ai[IOFF_WTOFF + c + 1] : ai[IOFF_KOOFF + c + 1];
    int nb = bEnd - bStart;
    const float* ZA = side ? ZcKO : ZcWT;
    const float* ZB = side ? ZcWT : ZcKO;
    int t = threadIdx.x, widx = t >> 6, lane = t & 63;
    float wsum = 0.f;
    if (nb > 0) {
        float inv_nb = 1.f / (float)nb;
        for (int ar = aStart + widx; ar < aEnd; ar += 16) {
            float za[10];
#pragma unroll
            for (int d = 0; d < 10; ++d) za[d] = ZA[d * 4096 + ar];
            float se = 0.f, ss = 0.f;
            for (int j = bStart + lane; j < bEnd; j += 64) {
                float s = 0.f;
#pragma unroll
                for (int d = 0; d < 10; ++d) s = fmaf(za[d], ZB[d * 4096 + j], s);
                s *= 10.f;                    // 1/TAU
                se += expf(s - 10.f);         // |S| <= 10
                ss += s;
            }
#pragma unroll
            for (int o = 32; o > 0; o >>= 1) { se += __shfl_xor(se, o, 64); ss += __shfl_xor(ss, o, 64); }
            if (lane == 0) wsum += (10.f + logf(se)) - ss * inv_nb;
        }
    }
    if (lane == 0) wsums[widx] = wsum;
    __syncthreads();
    if (t == 0) {
        float s = 0.f;
#pragma unroll
        for (int w = 0; w < 16; ++w) s += wsums[w];
        acc[(side ? OFF_L2 : OFF_L1) + c] = s;   // sole owner: plain store
    }
}

// ---------------- alignment stats + kappa: per-block partials (no global atomics) ----------------
__global__ __launch_bounds__(256) void align_kernel(const float* __restrict__ Z,
                                                    const int* __restrict__ wtl,
                                                    const int* __restrict__ kol,
                                                    const float* __restrict__ Kap,
                                                    float* __restrict__ Part)
{
    __shared__ float cL[10], qL[10], sL[100], ks;
    int t = threadIdx.x;
    if (t < 10) { cL[t] = 0.f; qL[t] = 0.f; }
    if (t < 100) sL[t] = 0.f;
    if (t == 0) ks = 0.f;
    __syncthreads();
    int row = blockIdx.x * 256 + t;
    int c = (row < 4096) ? wtl[row] : kol[row - 4096];
    float zz[10]; float q = 0.f;
#pragma unroll
    for (int d = 0; d < 10; ++d) { zz[d] = Z[(size_t)row * 10 + d]; q = fmaf(zz[d], zz[d], q); }
    atomicAdd(&cL[c], 1.f);
    atomicAdd(&qL[c], q);
#pragma unroll
    for (int d = 0; d < 10; ++d) atomicAdd(&sL[c * 10 + d], zz[d]);
    atomicAdd(&ks, Kap[row]);
    __syncthreads();
    float* pb = Part + (size_t)blockIdx.x * 128;
    if (t < 10)  { pb[t] = cL[t]; pb[10 + t] = qL[t]; }
    if (t < 100) pb[20 + t] = sL[t];
    if (t == 0)  pb[120] = ks;
}

__global__ void reduce_align_kernel(const float* __restrict__ Part, float* __restrict__ acc)
{
    int t = threadIdx.x;   // 128
    if (t < 120) {
        float s = 0.f;
        for (int b = 0; b < 32; ++b) s += Part[(size_t)b * 128 + t];
        if (t < 10)       acc[OFF_CNT + t] = s;
        else if (t < 20)  acc[OFF_ZSQ + t - 10] = s;
        else              acc[OFF_ZSUM + t - 20] = s;
    } else if (t == 120 || t == 121) {
        float s = 0.f;
        int b0 = (t - 120) * 16;
        for (int b = b0; b < b0 + 16; ++b) s += Part[(size_t)b * 128 + 120];
        acc[OFF_KSUM + (t - 120)] = s;
    }
}

// ---------------- finalize ----------------
__global__ void finalize_kernel(const float* __restrict__ acc, float* __restrict__ out)
{
    float total = 0.f, nsh = 0.f;
    for (int c = 0; c < 10; ++c) {
        float nw = acc[OFF_NWT + c], nk = acc[OFF_NKO + c];
        if (nw > 0.5f && nk > 0.5f) {
            float l1 = acc[OFF_L1 + c] / nw;
            float l2 = acc[OFF_L2 + c] / nk;
            total += 0.5f * (l1 + l2);
            nsh += 1.f;
        }
    }
    float contrast = (nsh > 0.f) ? total / nsh : 0.f;
    float ap = 0.f, np_ = 0.f;
    for (int c = 0; c < 10; ++c) {
        float cn = acc[OFF_CNT + c];
        if (cn > 0.5f) {
            float mu2 = 0.f;
            for (int d = 0; d < 10; ++d) {
                float mm = acc[OFF_ZSUM + c * 10 + d] / cn;
                mu2 = fmaf(mm, mm, mu2);
            }
            ap += acc[OFF_ZSQ + c] / cn - mu2;
            np_ += 1.f;
        }
    }
    float align = (np_ > 0.f) ? ap / np_ : 0.f;
    float kl = 0.01f * (acc[OFF_KSUM + 0] + acc[OFF_KSUM + 1]) * (1.f / 4096.f);
    float recon = acc[OFF_REC] * (1.f / 8192000.f);
    out[0] = recon + kl + 1.0f * contrast + 0.5f * align;
}

extern "C" void kernel_launch(void* const* d_in, const int* in_sizes, int n_in,
                              void* d_out, int out_size, void* d_ws, size_t ws_size,
                              hipStream_t stream)
{
    const float* wt_x   = (const float*)d_in[0];
    const float* ko_x   = (const float*)d_in[1];
    const int*   wtl    = (const int*)d_in[2];
    const int*   kol    = (const int*)d_in[3];
    const float* enc_w1 = (const float*)d_in[4];
    const float* enc_b1 = (const float*)d_in[5];
    const float* enc_g  = (const float*)d_in[6];
    const float* enc_be = (const float*)d_in[7];
    const float* enc_w2 = (const float*)d_in[8];
    const float* enc_b2 = (const float*)d_in[9];
    const float* kap_w1 = (const float*)d_in[10];
    const float* kap_b1 = (const float*)d_in[11];
    const float* kap_g  = (const float*)d_in[12];
    const float* kap_be = (const float*)d_in[13];
    const float* kap_w2 = (const float*)d_in[14];
    const float* kap_b2 = (const float*)d_in[15];
    const float* dw1    = (const float*)d_in[16];
    const float* db1    = (const float*)d_in[17];
    const float* dg     = (const float*)d_in[18];
    const float* dbe    = (const float*)d_in[19];
    const float* dw2    = (const float*)d_in[20];
    const float* db2    = (const float*)d_in[21];

    float* ws  = (float*)d_ws;
    float* acc = ws;
    __bf16* WThi = (__bf16*)(ws + WT_OFF);
    __bf16* WTlo = (__bf16*)(ws + WTLO_OFF);
    float* Hb  = ws + H_OFF;
    float* Zb  = ws + Z_OFF;
    float* Kap = ws + KAP_OFF;
    __bf16* Ahi  = (__bf16*)(ws + ACT_HI_OFF);
    __bf16* Alo  = (__bf16*)(ws + ACT_LO_OFF);
    __bf16* BThi = (__bf16*)(ws + BT_HI_OFF);
    __bf16* BTlo = (__bf16*)(ws + BT_LO_OFF);
    float* ZcKO = ws + ZCKO_OFF;
    float* ZcWT = ws + ZCWT_OFF;
    float* Part = ws + PART_OFF;

    hipMemsetAsync(acc, 0, ACC_FLOATS * sizeof(float), stream);
    pack_w_kernel<<<128, 256, 0, stream>>>(enc_w1, kap_w1, WThi, WTlo);
    counts_kernel<<<1, 1024, 0, stream>>>(wtl, kol, acc);
    gemm1_kernel<<<256, 512, 0, stream>>>(wt_x, ko_x, WThi, WTlo, Hb);
    stage2_kernel<<<8192, 128, 0, stream>>>(Hb, enc_b1, enc_g, enc_be, enc_w2, enc_b2,
                                            kap_b1, kap_g, kap_be, kap_w2, kap_b2, Zb, Kap);
    // H is dead from here; Act/BT/ZcT/Part overlay it
    pack_dw2_kernel<<<32, 256, 0, stream>>>(dw2, BThi, BTlo);
    dec_act_kernel<<<2048, 256, 0, stream>>>(Zb, dw1, db1, dg, dbe, Ahi, Alo);
    scatter_z_kernel<<<32, 256, 0, stream>>>(Zb, wtl, kol, acc, ZcWT, ZcKO);
    contrast_kernel<<<20, 1024, 0, stream>>>(ZcWT, ZcKO, acc);
    align_kernel<<<32, 256, 0, stream>>>(Zb, wtl, kol, Kap, Part);
    reduce_align_kernel<<<1, 128, 0, stream>>>(Part, acc);
    dec_gemm_kernel<<<256, 512, 0, stream>>>(Ahi, Alo, BThi, BTlo, wt_x, ko_x, db2, acc);
    finalize_kernel<<<1, 1, 0, stream>>>(acc, (float*)d_out);
}

// Round 7
// 226.149 us; speedup vs baseline: 2.7894x; 1.2475x over previous
//
#include <hip/hip_runtime.h>
#include <math.h>

typedef __attribute__((ext_vector_type(8))) __bf16 bf16x8;
typedef __attribute__((ext_vector_type(4))) float f32x4;

// ---- workspace layout (float offsets) ----
#define OFF_NWT   0
#define OFF_NKO   10
#define OFF_L1    20
#define OFF_L2    30
#define OFF_CNT   40
#define OFF_ZSUM  50
#define OFF_ZSQ   150
#define OFF_KSUM  160
#define OFF_REC   162
// int-typed slots (indices into the same float array, viewed as int*)
#define IOFF_WTOFF 192      // int wtOff[11]
#define IOFF_KOOFF 204      // int koOff[11]
#define IOFF_WTCTR 216      // int wtCtr[10]  (KOCTR = WTCTR+10, consecutive)
#define IOFF_KOCTR 226      // int koCtr[10]
#define ACC_FLOATS 256

#define WT_OFF    256                        // WThi [256][2048] bf16 = 262144 floats
#define WTLO_OFF  (WT_OFF + 262144)          // WTlo
#define H_OFF     (WTLO_OFF + 262144)        // H [8192][256] fp32 -- dead after stage2
#define Z_OFF     (H_OFF + 8192*256)         // Z [8192][10]
#define KAP_OFF   (Z_OFF + 8192*10)          // kappa [8192]

// overlays on the dead H region (written only after stage2 consumed H):
#define ACT_HI_OFF  H_OFF                    // Act_hi [8192][128] bf16 = 524288 floats
#define ACT_LO_OFF  (H_OFF + 524288)
#define BT_HI_OFF   (H_OFF + 1048576)        // BT_hi [2048][128] bf16 = 131072 floats
#define BT_LO_OFF   (H_OFF + 1179648)
#define ZCKO_OFF    (H_OFF + 1310720)        // ZcT_ko [10][4096] fp32
#define ZCWT_OFF    (H_OFF + 1351680)        // ZcT_wt [10][4096] fp32
#define PART_OFF    (H_OFF + 1392640)        // align partials [32][128] fp32 (ends < H_OFF+2097152)

// ---------------- pack: transpose + bf16 hi/lo split of [enc_w1|kap_w1] ----------------
__global__ __launch_bounds__(256) void pack_w_kernel(const float* __restrict__ enc_w1,
                                                     const float* __restrict__ kap_w1,
                                                     __bf16* __restrict__ WThi,
                                                     __bf16* __restrict__ WTlo)
{
    __shared__ float tile[64][65];
    int kt = blockIdx.x & 31;
    int ct = blockIdx.x >> 5;
    int k0 = kt * 64, c0 = ct * 64;
    int t = threadIdx.x;
    int lr = t >> 6, lc = t & 63;
#pragma unroll
    for (int i = 0; i < 16; ++i) {
        int k = k0 + lr + 4 * i;
        int c = c0 + lc;
        float v = 0.f;
        if (k < 2000) v = (c < 128) ? enc_w1[(size_t)k * 128 + c]
                                    : kap_w1[(size_t)k * 128 + (c - 128)];
        tile[lc][lr + 4 * i] = v;
    }
    __syncthreads();
#pragma unroll
    for (int i = 0; i < 16; ++i) {
        int c = c0 + lr + 4 * i;
        int k = k0 + lc;
        float v = tile[lr + 4 * i][lc];
        __bf16 h = (__bf16)v;
        __bf16 l = (__bf16)(v - (float)h);
        size_t idx = (size_t)c * 2048 + k;
        WThi[idx] = h;
        WTlo[idx] = l;
    }
}

// ---------------- pack: transpose + bf16 hi/lo split of dec_w2 [128][2000] -> BT [2048][128] ----
__global__ __launch_bounds__(256) void pack_dw2_kernel(const float* __restrict__ dw2,
                                                       __bf16* __restrict__ BThi,
                                                       __bf16* __restrict__ BTlo)
{
    __shared__ float tile[64][129];   // [jj][c]
    int j0 = blockIdx.x * 64;
    int t = threadIdx.x;
#pragma unroll
    for (int i = 0; i < 32; ++i) {
        int idx = i * 256 + t;
        int c = idx >> 6, jj = idx & 63;
        int j = j0 + jj;
        tile[jj][c] = (j < 2000) ? dw2[(size_t)c * 2000 + j] : 0.f;
    }
    __syncthreads();
#pragma unroll
    for (int i = 0; i < 32; ++i) {
        int idx = i * 256 + t;
        int jj = idx >> 7, c = idx & 127;
        float v = tile[jj][c];
        __bf16 h = (__bf16)v;
        size_t o = (size_t)(j0 + jj) * 128 + c;
        BThi[o] = h;
        BTlo[o] = (__bf16)(v - (float)h);
    }
}

// ---------------- class counts + prefix offsets ----------------
__global__ void counts_kernel(const int* __restrict__ wtl, const int* __restrict__ kol,
                              float* __restrict__ acc)
{
    __shared__ int cw[10], ck[10];
    int t = threadIdx.x;
    if (t < 10) { cw[t] = 0; ck[t] = 0; }
    __syncthreads();
    for (int i = t; i < 4096; i += 1024) {
        atomicAdd(&cw[wtl[i]], 1);
        atomicAdd(&ck[kol[i]], 1);
    }
    __syncthreads();
    if (t < 10) { acc[OFF_NWT + t] = (float)cw[t]; acc[OFF_NKO + t] = (float)ck[t]; }
    if (t == 0) {
        int* ai = (int*)acc;
        int aw = 0, ak = 0;
        for (int c = 0; c < 10; ++c) {
            ai[IOFF_WTOFF + c] = aw; aw += cw[c];
            ai[IOFF_KOOFF + c] = ak; ak += ck[c];
        }
        ai[IOFF_WTOFF + 10] = aw;
        ai[IOFF_KOOFF + 10] = ak;
    }
}

// ---------------- scatter Z into class-compacted TRANSPOSED arrays ----------------
__global__ __launch_bounds__(256) void scatter_z_kernel(const float* __restrict__ Z,
                                                        const int* __restrict__ wtl,
                                                        const int* __restrict__ kol,
                                                        float* __restrict__ acc,
                                                        float* __restrict__ ZcWT,
                                                        float* __restrict__ ZcKO)
{
    __shared__ int lcnt[20];
    __shared__ int lbase[20];
    int t = threadIdx.x;
    if (t < 20) lcnt[t] = 0;
    __syncthreads();
    int row = blockIdx.x * 256 + t;               // 0..8191
    int side = row >= 4096;                       // 0 = wt, 1 = ko
    int r = side ? row - 4096 : row;
    int c = side ? kol[r] : wtl[r];
    int key = side * 10 + c;
    int myrank = atomicAdd(&lcnt[key], 1);
    __syncthreads();
    int* ai = (int*)acc;
    if (t < 20 && lcnt[t] > 0)
        lbase[t] = atomicAdd(&ai[IOFF_WTCTR + t], lcnt[t]);   // WTCTR..KOCTR consecutive
    __syncthreads();
    int off = side ? ai[IOFF_KOOFF + c] : ai[IOFF_WTOFF + c];
    int slot = off + lbase[key] + myrank;
    float* dst = side ? ZcKO : ZcWT;
    const float* zr = Z + (size_t)row * 10;
#pragma unroll
    for (int d = 0; d < 10; ++d) dst[d * 4096 + slot] = zr[d];
}

// ---------------- GEMM1 (MFMA bf16x3): H[8192][256] = X[8192][2000] @ W[2000][256] ----------------
__global__ __launch_bounds__(512) void gemm1_kernel(const float* __restrict__ wt_x,
                                                    const float* __restrict__ ko_x,
                                                    const __bf16* __restrict__ WThi,
                                                    const __bf16* __restrict__ WTlo,
                                                    float* __restrict__ Hb)
{
    __shared__ short Bs[2][2][8192];   // [buf][hi/lo][unit*8 shorts] = 64 KB
    int t = threadIdx.x;
    int widx = t >> 6, lane = t & 63;
    int wm = widx >> 2, wn = widx & 3;
    int R0 = blockIdx.x * 32;
    const float* xb = (R0 < 4096) ? (wt_x + (size_t)R0 * 2000)
                                  : (ko_x + (size_t)(R0 - 4096) * 2000);
    int arow = wm * 16 + (lane & 15);
    const float* xrow = xb + (size_t)arow * 2000;
    int kboff = (lane >> 4) * 8;

    int cc0 = (t >> 2) & 15;
    int s0  = (t & 3) ^ ((cc0 >> 1) & 3);
    int col0 = (t >> 6) * 16 + cc0;
    size_t boff0 = (size_t)col0 * 2048 + s0 * 8;
    size_t boff1 = boff0 + (size_t)128 * 2048;

    f32x4 acc0, acc1, acc2, acc3;
#pragma unroll
    for (int r = 0; r < 4; ++r) { acc0[r] = 0.f; acc1[r] = 0.f; acc2[r] = 0.f; acc3[r] = 0.f; }

    uint4 bhA0, bhA1, blA0, blA1;
    uint4 bhB0, bhB1, blB0, blB1;
    float4 aA0, aA1, aB0, aB1;

#define GLOADB_(step, h0, h1, l0, l1) do { \
    h0 = *(const uint4*)(WThi + boff0 + (size_t)(step) * 32); \
    h1 = *(const uint4*)(WThi + boff1 + (size_t)(step) * 32); \
    l0 = *(const uint4*)(WTlo + boff0 + (size_t)(step) * 32); \
    l1 = *(const uint4*)(WTlo + boff1 + (size_t)(step) * 32); } while (0)

#define DSWRITE_(buf, h0, h1, l0, l1) do { \
    *(uint4*)&Bs[buf][0][t * 8]        = h0; \
    *(uint4*)&Bs[buf][0][4096 + t * 8] = h1; \
    *(uint4*)&Bs[buf][1][t * 8]        = l0; \
    *(uint4*)&Bs[buf][1][4096 + t * 8] = l1; } while (0)

#define GLOADA_(step, a0, a1) do { \
    int k0_ = (step) * 32; \
    int k_ = k0_ + kboff; \
    if (k0_ <= 1952) { \
        a0 = *(const float4*)(xrow + k_); \
        a1 = *(const float4*)(xrow + k_ + 4); \
    } else { \
        float t_[8]; \
        _Pragma("unroll") \
        for (int j = 0; j < 8; ++j) { int kk = k_ + j; t_[j] = (kk < 2000) ? xrow[kk] : 0.f; } \
        a0 = make_float4(t_[0], t_[1], t_[2], t_[3]); \
        a1 = make_float4(t_[4], t_[5], t_[6], t_[7]); } } while (0)

#define CONVA_(a0, a1, ahi, alo) do { \
    float av_[8] = {a0.x, a0.y, a0.z, a0.w, a1.x, a1.y, a1.z, a1.w}; \
    _Pragma("unroll") \
    for (int j = 0; j < 8; ++j) { \
        __bf16 h_ = (__bf16)av_[j]; \
        ahi[j] = h_; \
        alo[j] = (__bf16)(av_[j] - (float)h_); } } while (0)

#define MFMA_(buf) do { \
    _Pragma("unroll") \
    for (int nf = 0; nf < 4; ++nf) { \
        bf16x8 bhf = *(const bf16x8*)&Bs[buf][0][(ubase + nf * 64) * 8]; \
        bf16x8 blf = *(const bf16x8*)&Bs[buf][1][(ubase + nf * 64) * 8]; \
        f32x4* ac = (nf == 0) ? &acc0 : (nf == 1) ? &acc1 : (nf == 2) ? &acc2 : &acc3; \
        *ac = __builtin_amdgcn_mfma_f32_16x16x32_bf16(ahi, bhf, *ac, 0, 0, 0); \
        *ac = __builtin_amdgcn_mfma_f32_16x16x32_bf16(alo, bhf, *ac, 0, 0, 0); \
        *ac = __builtin_amdgcn_mfma_f32_16x16x32_bf16(ahi, blf, *ac, 0, 0, 0); } } while (0)

    GLOADB_(0, bhA0, bhA1, blA0, blA1); GLOADA_(0, aA0, aA1);
    GLOADB_(1, bhB0, bhB1, blB0, blB1); GLOADA_(1, aB0, aB1);
    DSWRITE_(0, bhA0, bhA1, blA0, blA1);
    __syncthreads();

    int cpr = lane & 15;
    int pph = (lane >> 4) ^ ((cpr >> 1) & 3);
    int ubase = (wn * 4) * 64 + cpr * 4 + pph;

    for (int it = 0; it < 32; ++it) {
        int st0 = it * 2;
        {
            bf16x8 ahi, alo;
            CONVA_(aA0, aA1, ahi, alo);
            if (st0 + 2 < 64) { GLOADB_(st0 + 2, bhA0, bhA1, blA0, blA1); GLOADA_(st0 + 2, aA0, aA1); }
            DSWRITE_(1, bhB0, bhB1, blB0, blB1);
            MFMA_(0);
            __syncthreads();
        }
        {
            bf16x8 ahi, alo;
            CONVA_(aB0, aB1, ahi, alo);
            if (st0 + 3 < 64) { GLOADB_(st0 + 3, bhB0, bhB1, blB0, blB1); GLOADA_(st0 + 3, aB0, aB1); }
            if (st0 + 2 < 64) DSWRITE_(0, bhA0, bhA1, blA0, blA1);
            MFMA_(1);
            __syncthreads();
        }
    }

#pragma unroll
    for (int r = 0; r < 4; ++r) {
        int row = R0 + wm * 16 + (lane >> 4) * 4 + r;
        size_t base = (size_t)row * 256 + wn * 64 + (lane & 15);
        Hb[base]      = acc0[r];
        Hb[base + 16] = acc1[r];
        Hb[base + 32] = acc2[r];
        Hb[base + 48] = acc3[r];
    }
#undef GLOADB_
#undef DSWRITE_
#undef GLOADA_
#undef CONVA_
#undef MFMA_
}

// ---------------- stage2: LN->ReLU->head matmuls per row ----------------
__global__ __launch_bounds__(128) void stage2_kernel(const float* __restrict__ Hb,
    const float* __restrict__ enc_b1, const float* __restrict__ enc_g, const float* __restrict__ enc_be,
    const float* __restrict__ enc_w2, const float* __restrict__ enc_b2,
    const float* __restrict__ kap_b1, const float* __restrict__ kap_g, const float* __restrict__ kap_be,
    const float* __restrict__ kap_w2, const float* __restrict__ kap_b2,
    float* __restrict__ Z, float* __restrict__ Kap)
{
    __shared__ float sh[128];
    int row  = blockIdx.x;
    int wave = threadIdx.x >> 6;
    int lane = threadIdx.x & 63;
    const float* hb = Hb + (size_t)row * 256 + wave * 128;
    const float* b1 = wave ? kap_b1 : enc_b1;
    const float* gg = wave ? kap_g  : enc_g;
    const float* bb = wave ? kap_be : enc_be;

    float h0 = hb[lane]      + b1[lane];
    float h1 = hb[lane + 64] + b1[lane + 64];
    float s = h0 + h1;
#pragma unroll
    for (int o = 32; o > 0; o >>= 1) s += __shfl_xor(s, o, 64);
    float m = s * (1.f / 128.f);
    float d0 = h0 - m, d1 = h1 - m;
    float v = d0 * d0 + d1 * d1;
#pragma unroll
    for (int o = 32; o > 0; o >>= 1) v += __shfl_xor(v, o, 64);
    v *= (1.f / 128.f);
    float sc = 1.f / sqrtf(v + 1e-5f);
    float r0 = fmaxf(fmaf(d0 * sc, gg[lane],      bb[lane]),      0.f);
    float r1 = fmaxf(fmaf(d1 * sc, gg[lane + 64], bb[lane + 64]), 0.f);

    if (wave == 0) { sh[lane] = r0; sh[lane + 64] = r1; }
    __syncthreads();

    if (wave == 0) {
        float mu = 0.f;
        if (lane < 10) {
            mu = enc_b2[lane];
            for (int c = 0; c < 128; ++c) mu = fmaf(sh[c], enc_w2[c * 10 + lane], mu);
        }
        float n2 = mu * mu;
#pragma unroll
        for (int o = 8; o > 0; o >>= 1) n2 += __shfl_xor(n2, o, 16);
        float inv = 1.f / fmaxf(sqrtf(n2), 1e-12f);
        if (lane < 10) Z[(size_t)row * 10 + lane] = mu * inv;
    } else {
        float p = r0 * kap_w2[lane] + r1 * kap_w2[lane + 64];
#pragma unroll
        for (int o = 32; o > 0; o >>= 1) p += __shfl_xor(p, o, 64);
        if (lane == 0) {
            float x = p + kap_b2[0];
            float sp = (x > 20.f) ? x : log1pf(expf(x));
            Kap[row] = sp + 1e-6f;
        }
    }
}

// ---------------- dec_act: a = ReLU(LN(z @ dw1 + db1)) -> bf16 hi/lo [8192][128] ----------------
__global__ __launch_bounds__(256) void dec_act_kernel(const float* __restrict__ Zb,
    const float* __restrict__ dw1, const float* __restrict__ db1,
    const float* __restrict__ dg,  const float* __restrict__ dbe,
    __bf16* __restrict__ Ahi, __bf16* __restrict__ Alo)
{
    int wave = threadIdx.x >> 6;
    int lane = threadIdx.x & 63;
    int row = blockIdx.x * 4 + wave;
    const float* zr = Zb + (size_t)row * 10;
    float z[10];
#pragma unroll
    for (int d = 0; d < 10; ++d) z[d] = zr[d];
    int c0 = lane, c1 = lane + 64;
    float h0 = db1[c0], h1 = db1[c1];
#pragma unroll
    for (int d = 0; d < 10; ++d) {
        h0 = fmaf(z[d], dw1[d * 128 + c0], h0);
        h1 = fmaf(z[d], dw1[d * 128 + c1], h1);
    }
    float s = h0 + h1;
#pragma unroll
    for (int o = 32; o > 0; o >>= 1) s += __shfl_xor(s, o, 64);
    float m = s * (1.f / 128.f);
    float d0 = h0 - m, d1 = h1 - m;
    float v = d0 * d0 + d1 * d1;
#pragma unroll
    for (int o = 32; o > 0; o >>= 1) v += __shfl_xor(v, o, 64);
    v *= (1.f / 128.f);
    float sc = 1.f / sqrtf(v + 1e-5f);
    float a0 = fmaxf(fmaf(d0 * sc, dg[c0], dbe[c0]), 0.f);
    float a1 = fmaxf(fmaf(d1 * sc, dg[c1], dbe[c1]), 0.f);
    __bf16 h0b = (__bf16)a0, h1b = (__bf16)a1;
    size_t base = (size_t)row * 128;
    Ahi[base + c0] = h0b;                 Ahi[base + c1] = h1b;
    Alo[base + c0] = (__bf16)(a0 - (float)h0b);
    Alo[base + c1] = (__bf16)(a1 - (float)h1b);
}

// ---------------- dec_gemm: rec = Act @ dw2 + b2, fused sq-err vs x (MFMA bf16x3) ----------------
__global__ __launch_bounds__(512) void dec_gemm_kernel(
    const __bf16* __restrict__ Ahi, const __bf16* __restrict__ Alo,
    const __bf16* __restrict__ BThi, const __bf16* __restrict__ BTlo,
    const float* __restrict__ wt_x, const float* __restrict__ ko_x,
    const float* __restrict__ db2, float* __restrict__ acc)
{
    __shared__ float rs[8];
    int t = threadIdx.x;
    int widx = t >> 6, lane = t & 63;
    int wm = widx >> 2, wn = widx & 3;
    int R0 = blockIdx.x * 32;
    const float* xbase = (R0 < 4096) ? wt_x : ko_x;
    int xr0 = ((R0 < 4096) ? R0 : R0 - 4096) + wm * 16 + (lane >> 4) * 4;

    size_t abase = (size_t)(R0 + wm * 16 + (lane & 15)) * 128 + (lane >> 4) * 8;
    bf16x8 ah0 = *(const bf16x8*)(Ahi + abase);
    bf16x8 ah1 = *(const bf16x8*)(Ahi + abase + 32);
    bf16x8 ah2 = *(const bf16x8*)(Ahi + abase + 64);
    bf16x8 ah3 = *(const bf16x8*)(Ahi + abase + 96);
    bf16x8 al0 = *(const bf16x8*)(Alo + abase);
    bf16x8 al1 = *(const bf16x8*)(Alo + abase + 32);
    bf16x8 al2 = *(const bf16x8*)(Alo + abase + 64);
    bf16x8 al3 = *(const bf16x8*)(Alo + abase + 96);

    float rsum = 0.f;
    for (int itn = 0; itn < 32; ++itn) {
        int col = itn * 64 + wn * 16 + (lane & 15);
        size_t bbase = (size_t)col * 128 + (lane >> 4) * 8;
        bf16x8 bh0 = *(const bf16x8*)(BThi + bbase);
        bf16x8 bh1 = *(const bf16x8*)(BThi + bbase + 32);
        bf16x8 bh2 = *(const bf16x8*)(BThi + bbase + 64);
        bf16x8 bh3 = *(const bf16x8*)(BThi + bbase + 96);
        bf16x8 bl0 = *(const bf16x8*)(BTlo + bbase);
        bf16x8 bl1 = *(const bf16x8*)(BTlo + bbase + 32);
        bf16x8 bl2 = *(const bf16x8*)(BTlo + bbase + 64);
        bf16x8 bl3 = *(const bf16x8*)(BTlo + bbase + 96);

        f32x4 a4;
#pragma unroll
        for (int r = 0; r < 4; ++r) a4[r] = 0.f;
        a4 = __builtin_amdgcn_mfma_f32_16x16x32_bf16(ah0, bh0, a4, 0, 0, 0);
        a4 = __builtin_amdgcn_mfma_f32_16x16x32_bf16(al0, bh0, a4, 0, 0, 0);
        a4 = __builtin_amdgcn_mfma_f32_16x16x32_bf16(ah0, bl0, a4, 0, 0, 0);
        a4 = __builtin_amdgcn_mfma_f32_16x16x32_bf16(ah1, bh1, a4, 0, 0, 0);
        a4 = __builtin_amdgcn_mfma_f32_16x16x32_bf16(al1, bh1, a4, 0, 0, 0);
        a4 = __builtin_amdgcn_mfma_f32_16x16x32_bf16(ah1, bl1, a4, 0, 0, 0);
        a4 = __builtin_amdgcn_mfma_f32_16x16x32_bf16(ah2, bh2, a4, 0, 0, 0);
        a4 = __builtin_amdgcn_mfma_f32_16x16x32_bf16(al2, bh2, a4, 0, 0, 0);
        a4 = __builtin_amdgcn_mfma_f32_16x16x32_bf16(ah2, bl2, a4, 0, 0, 0);
        a4 = __builtin_amdgcn_mfma_f32_16x16x32_bf16(ah3, bh3, a4, 0, 0, 0);
        a4 = __builtin_amdgcn_mfma_f32_16x16x32_bf16(al3, bh3, a4, 0, 0, 0);
        a4 = __builtin_amdgcn_mfma_f32_16x16x32_bf16(ah3, bl3, a4, 0, 0, 0);

        if (col < 2000) {
            float bb = db2[col];
#pragma unroll
            for (int r = 0; r < 4; ++r) {
                float xv = xbase[(size_t)(xr0 + r) * 2000 + col];
                float e = a4[r] + bb - xv;
                rsum = fmaf(e, e, rsum);
            }
        }
    }
#pragma unroll
    for (int o = 32; o > 0; o >>= 1) rsum += __shfl_xor(rsum, o, 64);
    if (lane == 0) rs[widx] = rsum;
    __syncthreads();
    if (t == 0) {
        float s = 0.f;
#pragma unroll
        for (int w = 0; w < 8; ++w) s += rs[w];
        atomicAdd(&acc[OFF_REC], s);
    }
}

// ---------------- contrast v4: lanes = A-rows, B-cols in LDS, 60 blocks ----------------
// Block b: cs = b/3 -> (class c = cs>>1, side = cs&1), sub = b%3 (row third).
// Each thread owns one A-row (za in regs, per-lane se/ss -> NO per-row reduction).
// Inner loop: wave-uniform LDS broadcast of one B-col per iteration.
#define MAXNB 768
__global__ __launch_bounds__(256) void contrast_kernel(const float* __restrict__ ZcWT,
                                                       const float* __restrict__ ZcKO,
                                                       float* __restrict__ acc)
{
    __shared__ float zb[MAXNB * 12];
    __shared__ float bsum[4];
    int b = blockIdx.x;
    int cs = b / 3, sub = b - cs * 3;
    int c = cs >> 1, side = cs & 1;
    const int* ai = (const int*)acc;
    int aStart = side ? ai[IOFF_KOOFF + c]     : ai[IOFF_WTOFF + c];
    int aEnd   = side ? ai[IOFF_KOOFF + c + 1] : ai[IOFF_WTOFF + c + 1];
    int bStart = side ? ai[IOFF_WTOFF + c]     : ai[IOFF_KOOFF + c];
    int bEnd   = side ? ai[IOFF_WTOFF + c + 1] : ai[IOFF_KOOFF + c + 1];
    int na = aEnd - aStart;
    int nb = bEnd - bStart;
    if (nb > MAXNB) nb = MAXNB;           // statistically impossible; memory safety
    const float* ZA = side ? ZcKO : ZcWT;
    const float* ZB = side ? ZcWT : ZcKO;
    int t = threadIdx.x;

    // stage B columns into LDS, transposed to [slot][12] (48B stride, 16B aligned)
    for (int u = t; u < nb; u += 256) {
#pragma unroll
        for (int d = 0; d < 10; ++d) zb[u * 12 + d] = ZB[d * 4096 + bStart + u];
    }
    __syncthreads();

    int chunk = (na + 2) / 3;             // <= 256 for na <= 766
    int r0 = sub * chunk;
    int rcnt = na - r0; if (rcnt > chunk) rcnt = chunk;

    float wsum = 0.f;
    bool waveActive = (nb > 0) && ((t & ~63) < rcnt);
    if (waveActive) {
        bool valid = t < rcnt;
        int ar = aStart + (valid ? (r0 + t) : 0);
        float za[10];
#pragma unroll
        for (int d = 0; d < 10; ++d) za[d] = ZA[d * 4096 + ar];
        float se = 0.f, ss = 0.f;
        for (int u = 0; u < nb; ++u) {
            const float* zp = &zb[u * 12];
            float s = 0.f;
#pragma unroll
            for (int d = 0; d < 10; ++d) s = fmaf(za[d], zp[d], s);
            s *= 10.f;                    // 1/TAU
            se += __expf(s - 10.f);       // |S| <= 10
            ss += s;
        }
        if (valid) wsum = (10.f + __logf(se)) - ss / (float)nb;
    }
#pragma unroll
    for (int o = 32; o > 0; o >>= 1) wsum += __shfl_xor(wsum, o, 64);
    if ((t & 63) == 0) bsum[t >> 6] = wsum;
    __syncthreads();
    if (t == 0) {
        float s = bsum[0] + bsum[1] + bsum[2] + bsum[3];
        if (s != 0.f || nb > 0)
            atomicAdd(&acc[(side ? OFF_L2 : OFF_L1) + c], s);
    }
}

// ---------------- alignment stats + kappa: per-block partials (no global atomics) ----------------
__global__ __launch_bounds__(256) void align_kernel(const float* __restrict__ Z,
                                                    const int* __restrict__ wtl,
                                                    const int* __restrict__ kol,
                                                    const float* __restrict__ Kap,
                                                    float* __restrict__ Part)
{
    __shared__ float cL[10], qL[10], sL[100], ks;
    int t = threadIdx.x;
    if (t < 10) { cL[t] = 0.f; qL[t] = 0.f; }
    if (t < 100) sL[t] = 0.f;
    if (t == 0) ks = 0.f;
    __syncthreads();
    int row = blockIdx.x * 256 + t;
    int c = (row < 4096) ? wtl[row] : kol[row - 4096];
    float zz[10]; float q = 0.f;
#pragma unroll
    for (int d = 0; d < 10; ++d) { zz[d] = Z[(size_t)row * 10 + d]; q = fmaf(zz[d], zz[d], q); }
    atomicAdd(&cL[c], 1.f);
    atomicAdd(&qL[c], q);
#pragma unroll
    for (int d = 0; d < 10; ++d) atomicAdd(&sL[c * 10 + d], zz[d]);
    atomicAdd(&ks, Kap[row]);
    __syncthreads();
    float* pb = Part + (size_t)blockIdx.x * 128;
    if (t < 10)  { pb[t] = cL[t]; pb[10 + t] = qL[t]; }
    if (t < 100) pb[20 + t] = sL[t];
    if (t == 0)  pb[120] = ks;
}

__global__ void reduce_align_kernel(const float* __restrict__ Part, float* __restrict__ acc)
{
    int t = threadIdx.x;   // 128
    if (t < 120) {
        float s = 0.f;
        for (int b = 0; b < 32; ++b) s += Part[(size_t)b * 128 + t];
        if (t < 10)       acc[OFF_CNT + t] = s;
        else if (t < 20)  acc[OFF_ZSQ + t - 10] = s;
        else              acc[OFF_ZSUM + t - 20] = s;
    } else if (t == 120 || t == 121) {
        float s = 0.f;
        int b0 = (t - 120) * 16;
        for (int b = b0; b < b0 + 16; ++b) s += Part[(size_t)b * 128 + 120];
        acc[OFF_KSUM + (t - 120)] = s;
    }
}

// ---------------- finalize ----------------
__global__ void finalize_kernel(const float* __restrict__ acc, float* __restrict__ out)
{
    float total = 0.f, nsh = 0.f;
    for (int c = 0; c < 10; ++c) {
        float nw = acc[OFF_NWT + c], nk = acc[OFF_NKO + c];
        if (nw > 0.5f && nk > 0.5f) {
            float l1 = acc[OFF_L1 + c] / nw;
            float l2 = acc[OFF_L2 + c] / nk;
            total += 0.5f * (l1 + l2);
            nsh += 1.f;
        }
    }
    float contrast = (nsh > 0.f) ? total / nsh : 0.f;
    float ap = 0.f, np_ = 0.f;
    for (int c = 0; c < 10; ++c) {
        float cn = acc[OFF_CNT + c];
        if (cn > 0.5f) {
            float mu2 = 0.f;
            for (int d = 0; d < 10; ++d) {
                float mm = acc[OFF_ZSUM + c * 10 + d] / cn;
                mu2 = fmaf(mm, mm, mu2);
            }
            ap += acc[OFF_ZSQ + c] / cn - mu2;
            np_ += 1.f;
        }
    }
    float align = (np_ > 0.f) ? ap / np_ : 0.f;
    float kl = 0.01f * (acc[OFF_KSUM + 0] + acc[OFF_KSUM + 1]) * (1.f / 4096.f);
    float recon = acc[OFF_REC] * (1.f / 8192000.f);
    out[0] = recon + kl + 1.0f * contrast + 0.5f * align;
}

extern "C" void kernel_launch(void* const* d_in, const int* in_sizes, int n_in,
                              void* d_out, int out_size, void* d_ws, size_t ws_size,
                              hipStream_t stream)
{
    const float* wt_x   = (const float*)d_in[0];
    const float* ko_x   = (const float*)d_in[1];
    const int*   wtl    = (const int*)d_in[2];
    const int*   kol    = (const int*)d_in[3];
    const float* enc_w1 = (const float*)d_in[4];
    const float* enc_b1 = (const float*)d_in[5];
    const float* enc_g  = (const float*)d_in[6];
    const float* enc_be = (const float*)d_in[7];
    const float* enc_w2 = (const float*)d_in[8];
    const float* enc_b2 = (const float*)d_in[9];
    const float* kap_w1 = (const float*)d_in[10];
    const float* kap_b1 = (const float*)d_in[11];
    const float* kap_g  = (const float*)d_in[12];
    const float* kap_be = (const float*)d_in[13];
    const float* kap_w2 = (const float*)d_in[14];
    const float* kap_b2 = (const float*)d_in[15];
    const float* dw1    = (const float*)d_in[16];
    const float* db1    = (const float*)d_in[17];
    const float* dg     = (const float*)d_in[18];
    const float* dbe    = (const float*)d_in[19];
    const float* dw2    = (const float*)d_in[20];
    const float* db2    = (const float*)d_in[21];

    float* ws  = (float*)d_ws;
    float* acc = ws;
    __bf16* WThi = (__bf16*)(ws + WT_OFF);
    __bf16* WTlo = (__bf16*)(ws + WTLO_OFF);
    float* Hb  = ws + H_OFF;
    float* Zb  = ws + Z_OFF;
    float* Kap = ws + KAP_OFF;
    __bf16* Ahi  = (__bf16*)(ws + ACT_HI_OFF);
    __bf16* Alo  = (__bf16*)(ws + ACT_LO_OFF);
    __bf16* BThi = (__bf16*)(ws + BT_HI_OFF);
    __bf16* BTlo = (__bf16*)(ws + BT_LO_OFF);
    float* ZcKO = ws + ZCKO_OFF;
    float* ZcWT = ws + ZCWT_OFF;
    float* Part = ws + PART_OFF;

    hipMemsetAsync(acc, 0, ACC_FLOATS * sizeof(float), stream);
    pack_w_kernel<<<128, 256, 0, stream>>>(enc_w1, kap_w1, WThi, WTlo);
    counts_kernel<<<1, 1024, 0, stream>>>(wtl, kol, acc);
    gemm1_kernel<<<256, 512, 0, stream>>>(wt_x, ko_x, WThi, WTlo, Hb);
    stage2_kernel<<<8192, 128, 0, stream>>>(Hb, enc_b1, enc_g, enc_be, enc_w2, enc_b2,
                                            kap_b1, kap_g, kap_be, kap_w2, kap_b2, Zb, Kap);
    // H is dead from here; Act/BT/ZcT/Part overlay it
    pack_dw2_kernel<<<32, 256, 0, stream>>>(dw2, BThi, BTlo);
    dec_act_kernel<<<2048, 256, 0, stream>>>(Zb, dw1, db1, dg, dbe, Ahi, Alo);
    scatter_z_kernel<<<32, 256, 0, stream>>>(Zb, wtl, kol, acc, ZcWT, ZcKO);
    contrast_kernel<<<60, 256, 0, stream>>>(ZcWT, ZcKO, acc);
    align_kernel<<<32, 256, 0, stream>>>(Zb, wtl, kol, Kap, Part);
    reduce_align_kernel<<<1, 128, 0, stream>>>(Part, acc);
    dec_gemm_kernel<<<256, 512, 0, stream>>>(Ahi, Alo, BThi, BTlo, wt_x, ko_x, db2, acc);
    finalize_kernel<<<1, 1, 0, stream>>>(acc, (float*)d_out);
}